// Round 4
// baseline (1858.855 us; speedup 1.0000x reference)
//
#include <hip/hip_runtime.h>
#include <hip/hip_bf16.h>

// Model: BiGRU encoder (B=128, S=512, E=32, Hh=64) + gated enc_outs +
// 15-step attention GRU decoder (H=128) + logits GEMM (1920x32000x128).
// fp32 inputs/outputs; bf16 internal staging (outputs, enc, h_all, W1b, Woutb).
//
// R8: R7's asm volatile("" ::: "memory") clobber was forcing the compiler to
//     re-read Whh from memory every step (it may-alias "all memory"), which is
//     why VGPR_Count stayed 136 and VALUBusy fell to 10.9% with ~1900 stall
//     cyc/step. The clobber is unnecessary: the per-step store hs[j] (runtime
//     j) may-alias every later hs[k] read, so reload + ordering of hs is
//     already forced; weights/gi are free to hoist.
//     Changes: (a) clobber removed; (b) hs aligned 16B for ds_read_b128;
//     (c) step loop unrolled x4 with 4-deep statically-named gi prefetch
//     (covers ~900cy HBM latency; OOB prefetches stay inside gi buffer).

typedef unsigned short u16;
typedef unsigned int u32;
typedef __attribute__((ext_vector_type(8))) short short8;
typedef __attribute__((ext_vector_type(4))) float f32x4;

#define V_ 32000
#define E_ 32
#define H_ 128
#define B_ 128
#define S_ 512
#define TDEC 15   // T-1

__device__ __forceinline__ float bfu(u32 u) {
    union { u32 i; float f; } v; v.i = u << 16; return v.f;
}
__device__ __forceinline__ u16 f2bf(float f) {
    union { float f; u32 i; } v; v.f = f;
    u32 x = v.i;
    u32 r = (x + 0x7fffu + ((x >> 16) & 1u)) >> 16;
    return (u16)r;
}
__device__ __forceinline__ void bf8_to_f(const uint4 p, float* f) {
    f[0] = bfu(p.x & 0xffffu); f[1] = bfu(p.x >> 16);
    f[2] = bfu(p.y & 0xffffu); f[3] = bfu(p.y >> 16);
    f[4] = bfu(p.z & 0xffffu); f[5] = bfu(p.z >> 16);
    f[6] = bfu(p.w & 0xffffu); f[7] = bfu(p.w >> 16);
}
__device__ __forceinline__ float sigm(float x) { return 1.f / (1.f + expf(-x)); }
__device__ __forceinline__ float sigm_fast(float x) { return 1.f / (1.f + __expf(-x)); }
__device__ __forceinline__ float tanh_fast(float x) {
    const float t = __expf(2.f * x);          // args bounded ~|x|<12 here: no overflow
    return (t - 1.f) / (t + 1.f);
}

// ---------------------------------------------------------------------------
// K0: gi[dir][b][s][192] = embeds[b][s] . Wih_dir^T + bih (+ bhh for gates r,z).
// No sequential dependence -> fully parallel. grid = 1024 (b, s-chunk of 64),
// block = 384 (one thread per output column: 2 dirs x 192).
// ---------------------------------------------------------------------------
__global__ __launch_bounds__(384) void gi_kernel(
    const int* __restrict__ inputs, const float* __restrict__ emb,
    const float* __restrict__ Wih_f, const float* __restrict__ bih_f,
    const float* __restrict__ bhh_f,
    const float* __restrict__ Wih_b, const float* __restrict__ bih_b,
    const float* __restrict__ bhh_b,
    float* __restrict__ gi)
{
    const int b  = blockIdx.x >> 3;
    const int s0 = (blockIdx.x & 7) << 6;
    const int tid = threadIdx.x;

    __shared__ float xs[64][E_];   // 8 KB
    __shared__ int idx[64];
    if (tid < 64) idx[tid] = inputs[b * S_ + s0 + tid];
    __syncthreads();
    for (int i = tid; i < 64 * E_; i += 384) {
        xs[i >> 5][i & 31] = emb[(unsigned)idx[i >> 5] * E_ + (i & 31)];
    }
    __syncthreads();

    const int dir = (tid >= 192) ? 1 : 0;
    const int j = tid - dir * 192;               // 0..191: gate*64 + elem
    const float* Wih = dir ? Wih_b : Wih_f;
    const float* bih = dir ? bih_b : bih_f;
    const float* bhh = dir ? bhh_b : bhh_f;

    float w[E_];
    #pragma unroll
    for (int k = 0; k < E_; k += 4)
        *(float4*)(w + k) = *(const float4*)(Wih + j * E_ + k);
    // fold both biases for r,z (j<128); only b_ih for n (b_hh[n] stays inside r*(...))
    const float c = bih[j] + (j < 128 ? bhh[j] : 0.f);

    float* gout = gi + (((size_t)(dir * B_ + b)) * S_ + s0) * 192 + j;
    for (int r = 0; r < 64; r++) {
        const float4* xr = (const float4*)xs[r];   // uniform addr -> LDS broadcast
        float a0 = 0.f, a1 = 0.f, a2 = 0.f, a3 = 0.f;
        #pragma unroll
        for (int q = 0; q < E_ / 4; q++) {
            const float4 x = xr[q];
            a0 += x.x * w[4 * q + 0]; a1 += x.y * w[4 * q + 1];
            a2 += x.z * w[4 * q + 2]; a3 += x.w * w[4 * q + 3];
        }
        gout[(size_t)r * 192] = ((a0 + a1) + (a2 + a3)) + c;   // coalesced per r
    }
}

// ---------------------------------------------------------------------------
// K1: encoder BiGRU recurrence only. grid = 256 (b, dir), block = 64 = 1 wave.
// Lane j owns gate rows j, 64+j, 128+j of Whh (48 x f32x4 = 192 fp32 in regs)
// and state element h[j]. h broadcast via 256B LDS (uniform-addr ds_read_b128).
// NO barrier, NO memory clobber: the runtime-indexed store hs[j] may-alias all
// later hs reads, which forces per-step reload + ordering, while Whh/gi loads
// remain hoistable. Single wave -> lockstep, DS pipe in order.
// gi streamed from global with a 4-deep statically-named prefetch pipeline.
// outputs: bf16 [B][S][H]; sn: fp32 [B][H].
// ---------------------------------------------------------------------------
__global__ __launch_bounds__(64, 1) void encoder_kernel(
    const float* __restrict__ gi,
    const float* __restrict__ Whh_f, const float* __restrict__ bhh_f,
    const float* __restrict__ Whh_b, const float* __restrict__ bhh_b,
    u16* __restrict__ outputs, float* __restrict__ sn)
{
    const int j = threadIdx.x;              // 0..63
    const int b = blockIdx.x & 127;
    const int dir = blockIdx.x >> 7;

    const float* Whh = dir ? Whh_b : Whh_f;
    const float bh2 = (dir ? bhh_b : bhh_f)[128 + j];

    // Weights as native vector values, constant-indexed only -> SROA to VGPRs;
    // with no clobber in the loop these are loop-invariant and stay resident.
    f32x4 w0[16], w1[16], w2[16];
    {
        const f32x4* r0 = (const f32x4*)(Whh + j * 64);
        const f32x4* r1 = (const f32x4*)(Whh + (64 + j) * 64);
        const f32x4* r2 = (const f32x4*)(Whh + (128 + j) * 64);
        #pragma unroll
        for (int k = 0; k < 16; k++) {
            w0[k] = r0[k];
            w1[k] = r1[k];
            w2[k] = r2[k];
        }
    }

    __shared__ __attribute__((aligned(16))) float hs[64];
    hs[j] = 0.f;
    float hmine = 0.f;

    const float* gp = gi + ((size_t)(dir * B_ + b)) * S_ * 192 + j;
    u16* orow = outputs + ((size_t)b * S_) * H_ + (dir << 6) + j;

    const int st = dir ? -1 : 1;
    int oc = dir ? (S_ - 1) : 0;

    // 4-deep gi prefetch pipeline (12 scalars). Out-of-range step indices
    // (up to oc+-4) stay inside the gi allocation: fwd chains (0..127) overrun
    // into the next chain's region, bwd chains (128..255) underrun into the
    // previous chain's region; values are never consumed.
    float p00, p01, p02, p10, p11, p12, p20, p21, p22, p30, p31, p32;
    {
        const long o0 = (long)oc * 192;
        const long d  = (long)st * 192;
        p00 = gp[o0];         p01 = gp[o0 + 64];         p02 = gp[o0 + 128];
        p10 = gp[o0 + d];     p11 = gp[o0 + d + 64];     p12 = gp[o0 + d + 128];
        p20 = gp[o0 + 2*d];   p21 = gp[o0 + 2*d + 64];   p22 = gp[o0 + 2*d + 128];
        p30 = gp[o0 + 3*d];   p31 = gp[o0 + 3*d + 64];   p32 = gp[o0 + 3*d + 128];
    }

#define ENC_STEP(PA, PB, PC)                                                   \
    {                                                                          \
        const float g0 = PA, g1 = PB, g2 = PC;                                 \
        const long pf = (long)(oc + 4 * st) * 192;                             \
        PA = gp[pf]; PB = gp[pf + 64]; PC = gp[pf + 128];                      \
        float gh0a = 0.f, gh0b = 0.f, gh1a = 0.f,                              \
              gh1b = 0.f, gh2a = 0.f, gh2b = 0.f;                              \
        _Pragma("unroll")                                                      \
        for (int q = 0; q < 16; q += 2) {                                      \
            const f32x4 ha = *(const f32x4*)(hs + 4 * q);                      \
            const f32x4 hb = *(const f32x4*)(hs + 4 * q + 4);                  \
            gh0a += ha[0]*w0[q][0] + ha[1]*w0[q][1] + ha[2]*w0[q][2] + ha[3]*w0[q][3]; \
            gh1a += ha[0]*w1[q][0] + ha[1]*w1[q][1] + ha[2]*w1[q][2] + ha[3]*w1[q][3]; \
            gh2a += ha[0]*w2[q][0] + ha[1]*w2[q][1] + ha[2]*w2[q][2] + ha[3]*w2[q][3]; \
            gh0b += hb[0]*w0[q+1][0] + hb[1]*w0[q+1][1] + hb[2]*w0[q+1][2] + hb[3]*w0[q+1][3]; \
            gh1b += hb[0]*w1[q+1][0] + hb[1]*w1[q+1][1] + hb[2]*w1[q+1][2] + hb[3]*w1[q+1][3]; \
            gh2b += hb[0]*w2[q+1][0] + hb[1]*w2[q+1][1] + hb[2]*w2[q+1][2] + hb[3]*w2[q+1][3]; \
        }                                                                      \
        const float r = sigm_fast(g0 + gh0a + gh0b);                           \
        const float z = sigm_fast(g1 + gh1a + gh1b);                           \
        const float n = tanh_fast(g2 + r * (gh2a + gh2b + bh2));               \
        const float hn = n + z * (hmine - n);                                  \
        hmine = hn;                                                            \
        hs[j] = hn;                                                            \
        orow[(long)oc * H_] = f2bf(hn);                                        \
        oc += st;                                                              \
    }

    for (int s = 0; s < S_; s += 4) {
        ENC_STEP(p00, p01, p02)
        ENC_STEP(p10, p11, p12)
        ENC_STEP(p20, p21, p22)
        ENC_STEP(p30, p31, p32)
    }
#undef ENC_STEP

    sn[(b << 7) + (dir << 6) + j] = hmine;
}

// ---------------------------------------------------------------------------
// K2: t2[b][h] = sn[b] . W2[h] + b2[h].  grid=128, block=128. All fp32.
// ---------------------------------------------------------------------------
__global__ __launch_bounds__(128) void t2_kernel(
    const float* __restrict__ sn, const float* __restrict__ W2,
    const float* __restrict__ b2, float* __restrict__ t2)
{
    const int b = blockIdx.x, h = threadIdx.x;
    __shared__ float s_[H_];
    s_[h] = sn[b * H_ + h];
    __syncthreads();
    const float4* wr = (const float4*)(W2 + h * H_);
    float a0 = 0.f, a1 = 0.f, a2 = 0.f, a3 = 0.f;
    #pragma unroll 4
    for (int k = 0; k < H_ / 4; k++) {
        const float4 p = wr[k];
        a0 += s_[4 * k + 0] * p.x; a1 += s_[4 * k + 1] * p.y;
        a2 += s_[4 * k + 2] * p.z; a3 += s_[4 * k + 3] * p.w;
    }
    t2[b * H_ + h] = ((a0 + a1) + (a2 + a3)) + b2[h];
}

// ---------------------------------------------------------------------------
// K3: fp32 -> bf16 conversion (used for W1 and W_out). 4 elems/thread.
// ---------------------------------------------------------------------------
__global__ __launch_bounds__(256) void cvt_bf16_kernel(
    const float* __restrict__ src, u16* __restrict__ dst)
{
    const int i = (blockIdx.x * 256 + threadIdx.x) * 4;
    const float4 p = *(const float4*)(src + i);
    ushort4 q;
    q.x = f2bf(p.x); q.y = f2bf(p.y); q.z = f2bf(p.z); q.w = f2bf(p.w);
    *(ushort4*)(dst + i) = q;
}

// ---------------------------------------------------------------------------
// K4: gate via MFMA. pre[m][n] = outputs[m] . W1[n];
// enc[m][n] = outputs[m][n] * sigmoid(pre + b1[n] + t2[b][n]),  b = m>>9.
// M=65536 rows, N=128, K=128. Block = 4 waves, tile 64(M)x128(N). grid=1024.
// ---------------------------------------------------------------------------
__global__ __launch_bounds__(256) void gate_mfma_kernel(
    const u16* __restrict__ outputs, const u16* __restrict__ W1b,
    const float* __restrict__ b1, const float* __restrict__ t2,
    u16* __restrict__ enc)
{
    const int l = threadIdx.x & 63;
    const int w = threadIdx.x >> 6;
    const int tile_m = blockIdx.x * 64 + w * 16;
    const int row_a = tile_m + (l & 15);
    const int kb = (l >> 4) * 8;
    const int b = blockIdx.x >> 3;           // 8 blocks of 64 rows per batch

    f32x4 acc[8] = {};
    #pragma unroll
    for (int kk = 0; kk < 4; kk++) {
        const int k0 = kk * 32 + kb;
        const short8 af = *(const short8*)(outputs + row_a * H_ + k0);
        #pragma unroll
        for (int i = 0; i < 8; i++) {
            const int n = i * 16 + (l & 15);
            const short8 bv = *(const short8*)(W1b + n * H_ + k0);
            acc[i] = __builtin_amdgcn_mfma_f32_16x16x32_bf16(af, bv, acc[i], 0, 0, 0);
        }
    }

    const int m_base = tile_m + (l >> 4) * 4;
    #pragma unroll
    for (int i = 0; i < 8; i++) {
        const int n = i * 16 + (l & 15);
        const float bias = b1[n] + t2[b * H_ + n];
        #pragma unroll
        for (int r = 0; r < 4; r++) {
            const int m = m_base + r;
            const float g = sigm_fast(acc[i][r] + bias);
            const float o = bfu(outputs[m * H_ + n]);
            enc[m * H_ + n] = f2bf(o * g);
        }
    }
}

// ---------------------------------------------------------------------------
// K5: decoder. grid = 128 (one WG per batch), block = 256. 15 steps:
// attention (softmax over S=512, enc bf16) + GRU (fp32 weights).
// ---------------------------------------------------------------------------
__global__ __launch_bounds__(256) void decoder_kernel(
    const int* __restrict__ targets, const float* __restrict__ emb,
    const float* __restrict__ Wihd, const float* __restrict__ Whhd,
    const float* __restrict__ bihd, const float* __restrict__ bhhd,
    const u16* __restrict__ enc, const float* __restrict__ sn,
    u16* __restrict__ h_all)
{
    const int b = blockIdx.x;
    const int tid = threadIdx.x;
    __shared__ float h[H_];
    __shared__ float sc[S_];
    __shared__ float xv[H_ + E_];     // [c(128), e(32)]
    __shared__ float red[256];
    __shared__ float chalf[2][H_];
    __shared__ float sgi[3 * H_];
    __shared__ float sgh[3 * H_];

    if (tid < H_) h[tid] = sn[b * H_ + tid];
    __syncthreads();

    const u16* encb = enc + b * S_ * H_;

    for (int t = 0; t < TDEC; t++) {
        const int word = targets[b * 16 + t];

        // ---- pass 1: scores sc[s] = h . enc[b][s] ----
        for (int s = tid; s < S_; s += 256) {
            const u16* row = encb + s * H_;
            float a0 = 0.f, a1 = 0.f, a2 = 0.f, a3 = 0.f;
            for (int k = 0; k < H_; k += 8) {
                uint4 p = *(const uint4*)(row + k);
                float f[8]; bf8_to_f(p, f);
                a0 += h[k + 0] * f[0]; a1 += h[k + 1] * f[1];
                a2 += h[k + 2] * f[2]; a3 += h[k + 3] * f[3];
                a0 += h[k + 4] * f[4]; a1 += h[k + 5] * f[5];
                a2 += h[k + 6] * f[6]; a3 += h[k + 7] * f[7];
            }
            sc[s] = (a0 + a1) + (a2 + a3);
        }
        __syncthreads();

        // ---- softmax over 512 ----
        red[tid] = fmaxf(sc[tid], sc[tid + 256]);
        __syncthreads();
        for (int off = 128; off > 0; off >>= 1) {
            if (tid < off) red[tid] = fmaxf(red[tid], red[tid + off]);
            __syncthreads();
        }
        const float m = red[0];
        __syncthreads();
        const float e0 = expf(sc[tid] - m);
        const float e1 = expf(sc[tid + 256] - m);
        red[tid] = e0 + e1;
        __syncthreads();
        for (int off = 128; off > 0; off >>= 1) {
            if (tid < off) red[tid] = red[tid] + red[tid + off];
            __syncthreads();
        }
        const float inv = 1.f / red[0];
        __syncthreads();
        sc[tid] = e0 * inv;
        sc[tid + 256] = e1 * inv;
        __syncthreads();

        // ---- pass 2: c[k] = sum_s alpha[s] * enc[b][s][k] ----
        {
            const int k = tid & 127;
            const int half = tid >> 7;
            const u16* basep = encb + (half * 256) * H_ + k;
            const float* al = sc + half * 256;
            float c0 = 0.f, c1 = 0.f, c2 = 0.f, c3 = 0.f;
            for (int s = 0; s < 256; s += 4) {
                c0 += al[s + 0] * bfu(basep[(s + 0) * H_]);
                c1 += al[s + 1] * bfu(basep[(s + 1) * H_]);
                c2 += al[s + 2] * bfu(basep[(s + 2) * H_]);
                c3 += al[s + 3] * bfu(basep[(s + 3) * H_]);
            }
            chalf[half][k] = (c0 + c1) + (c2 + c3);
        }
        __syncthreads();
        if (tid < H_) xv[tid] = chalf[0][tid] + chalf[1][tid];
        else if (tid < H_ + E_) xv[tid] = emb[(unsigned)word * E_ + (tid - H_)];
        __syncthreads();

        // ---- gates ----
        for (int j = tid; j < 3 * H_; j += 256) {
            const float4* wr = (const float4*)(Wihd + j * (H_ + E_));
            float a0 = 0.f, a1 = 0.f, a2 = 0.f, a3 = 0.f;
            for (int k = 0; k < (H_ + E_) / 4; k++) {
                const float4 p = wr[k];
                a0 += xv[4 * k + 0] * p.x; a1 += xv[4 * k + 1] * p.y;
                a2 += xv[4 * k + 2] * p.z; a3 += xv[4 * k + 3] * p.w;
            }
            sgi[j] = ((a0 + a1) + (a2 + a3)) + bihd[j];

            const float4* hr = (const float4*)(Whhd + j * H_);
            float b0 = 0.f, b1_ = 0.f, b2_ = 0.f, b3 = 0.f;
            for (int k = 0; k < H_ / 4; k++) {
                const float4 p = hr[k];
                b0  += h[4 * k + 0] * p.x; b1_ += h[4 * k + 1] * p.y;
                b2_ += h[4 * k + 2] * p.z; b3  += h[4 * k + 3] * p.w;
            }
            sgh[j] = ((b0 + b1_) + (b2_ + b3)) + bhhd[j];
        }
        __syncthreads();

        if (tid < H_) {
            const float r = sigm(sgi[tid] + sgh[tid]);
            const float z = sigm(sgi[H_ + tid] + sgh[H_ + tid]);
            const float n = tanhf(sgi[2 * H_ + tid] + r * sgh[2 * H_ + tid]);
            const float hn = (1.f - z) * n + z * h[tid];
            h[tid] = hn;
            h_all[(t * B_ + b) * H_ + tid] = f2bf(hn);
        }
        __syncthreads();
    }
}

// ---------------------------------------------------------------------------
// K6: logits = h_all @ Woutb^T + b_out. MFMA bf16 NT GEMM, fp32 out.
// M=1920 (t*128+b), N=32000, K=128. grid=(500,30), block=256.
// Output: out[(b*15 + t)*32000 + n], fp32.
// ---------------------------------------------------------------------------
__global__ __launch_bounds__(256) void logits_kernel(
    const u16* __restrict__ hall, const u16* __restrict__ Woutb,
    const float* __restrict__ bout, float* __restrict__ out)
{
    const int l = threadIdx.x & 63;
    const int w = threadIdx.x >> 6;
    const int tile_n = blockIdx.x * 64;
    const int tile_m = blockIdx.y * 64 + w * 16;

    f32x4 acc[4] = {};
    const int row_a = tile_m + (l & 15);
    const int kb = (l >> 4) * 8;

    #pragma unroll
    for (int kk = 0; kk < 4; kk++) {
        const int k0 = kk * 32 + kb;
        const short8 af = *(const short8*)(hall + row_a * H_ + k0);
        #pragma unroll
        for (int i = 0; i < 4; i++) {
            const int n = tile_n + i * 16 + (l & 15);
            const short8 bv = *(const short8*)(Woutb + n * H_ + k0);
            acc[i] = __builtin_amdgcn_mfma_f32_16x16x32_bf16(af, bv, acc[i], 0, 0, 0);
        }
    }

    const int m_base = tile_m + (l >> 4) * 4;
    #pragma unroll
    for (int i = 0; i < 4; i++) {
        const int n = tile_n + i * 16 + (l & 15);
        const float bias = bout[n];
        #pragma unroll
        for (int r = 0; r < 4; r++) {
            const int m = m_base + r;
            const int t = m >> 7;
            const int bb = m & 127;
            out[(size_t)(bb * TDEC + t) * V_ + n] = acc[i][r] + bias;
        }
    }
}

// ---------------------------------------------------------------------------
extern "C" void kernel_launch(void* const* d_in, const int* in_sizes, int n_in,
                              void* d_out, int out_size, void* d_ws, size_t ws_size,
                              hipStream_t stream) {
    const int*   inputs  = (const int*)d_in[0];
    const int*   targets = (const int*)d_in[1];
    const float* emb     = (const float*)d_in[2];
    const float* Wih_f   = (const float*)d_in[3];
    const float* Whh_f   = (const float*)d_in[4];
    const float* bih_f   = (const float*)d_in[5];
    const float* bhh_f   = (const float*)d_in[6];
    const float* Wih_b   = (const float*)d_in[7];
    const float* Whh_b   = (const float*)d_in[8];
    const float* bih_b   = (const float*)d_in[9];
    const float* bhh_b   = (const float*)d_in[10];
    const float* W1      = (const float*)d_in[11];
    const float* b1      = (const float*)d_in[12];
    const float* W2      = (const float*)d_in[13];
    const float* b2      = (const float*)d_in[14];
    const float* Wihd    = (const float*)d_in[15];
    const float* Whhd    = (const float*)d_in[16];
    const float* bihd    = (const float*)d_in[17];
    const float* bhhd    = (const float*)d_in[18];
    const float* Wout    = (const float*)d_in[19];
    const float* bout    = (const float*)d_in[20];
    float* out = (float*)d_out;

    // Staging at the front of d_out (245.76 MB). The logits kernel runs last
    // and overwrites every element of d_out with the real output.
    u16*   outputs = (u16*)d_out;                       // bf16 B*S*H = 16,777,216 B
    u16*   enc     = (u16*)((char*)d_out + 16777216);   // bf16 B*S*H = 16,777,216 B
    u16*   W1b     = (u16*)((char*)d_out + 33554432);   // bf16 H*H   =     32,768 B
    float* gi      = (float*)((char*)d_out + 33619968); // f32 2*B*S*192 = 100,663,296 B (ends @134MB < 245MB)

    // d_ws: small state only (8.82 MB total) — layout validated in R3.
    char* ws = (char*)d_ws;
    float* sn    = (float*)(ws);                 // B*H  f32    =  65,536 B
    float* t2    = (float*)(ws + 65536);         // B*H  f32    =  65,536 B
    u16*   h_all = (u16*)(ws + 131072);          // 15*B*H bf16 = 491,520 B
    u16*   Woutb = (u16*)(ws + 622592);          // V*H bf16    = 8,192,000 B

    gi_kernel<<<B_ * (S_ / 64), 384, 0, stream>>>(inputs, emb, Wih_f, bih_f, bhh_f,
                                                  Wih_b, bih_b, bhh_b, gi);
    encoder_kernel<<<256, 64, 0, stream>>>(gi, Whh_f, bhh_f, Whh_b, bhh_b, outputs, sn);
    t2_kernel<<<128, 128, 0, stream>>>(sn, W2, b2, t2);
    cvt_bf16_kernel<<<H_ * H_ / 1024, 256, 0, stream>>>(W1, W1b);
    cvt_bf16_kernel<<<V_ * H_ / 1024, 256, 0, stream>>>(Wout, Woutb);
    gate_mfma_kernel<<<B_ * S_ / 64, 256, 0, stream>>>(outputs, W1b, b1, t2, enc);
    decoder_kernel<<<128, 256, 0, stream>>>(targets, emb, Wihd, Whhd, bihd, bhhd,
                                            enc, sn, h_all);
    logits_kernel<<<dim3(500, 30), 256, 0, stream>>>(h_all, Woutb, bout, out);
}

// Round 5
// 1042.364 us; speedup vs baseline: 1.7833x; 1.7833x over previous
//
#include <hip/hip_runtime.h>
#include <hip/hip_bf16.h>

// Model: BiGRU encoder (B=128, S=512, E=32, Hh=64) + gated enc_outs +
// 15-step attention GRU decoder (H=128) + logits GEMM (1920x32000x128).
// fp32 inputs/outputs; bf16 internal staging (outputs, enc, h_all, W1b, Woutb).
//
// R9: R8 spilled in-loop (VGPR_Count 256 = ceiling, WRITE_SIZE doubled with
//     scratch stores, VALUBusy 6.4%): 192 weight floats/lane + 4x unroll
//     exceeds the register file. Fix: STOP requiring 192 regs/lane.
//     Encoder restructured as 3 waves/block (192 thr), wave g owns gate g:
//     64 weight floats/lane (16 x f32x4), one 64-long dot per step per lane.
//     Gates combined via LDS sg[256]; wave 0 does activations + h update +
//     output store. 2 barriers/step; gi prefetched 2 steps ahead.
//     Register need ~100 VGPR -> no spill possible.

typedef unsigned short u16;
typedef unsigned int u32;
typedef __attribute__((ext_vector_type(8))) short short8;
typedef __attribute__((ext_vector_type(4))) float f32x4;

#define V_ 32000
#define E_ 32
#define H_ 128
#define B_ 128
#define S_ 512
#define TDEC 15   // T-1

__device__ __forceinline__ float bfu(u32 u) {
    union { u32 i; float f; } v; v.i = u << 16; return v.f;
}
__device__ __forceinline__ u16 f2bf(float f) {
    union { float f; u32 i; } v; v.f = f;
    u32 x = v.i;
    u32 r = (x + 0x7fffu + ((x >> 16) & 1u)) >> 16;
    return (u16)r;
}
__device__ __forceinline__ void bf8_to_f(const uint4 p, float* f) {
    f[0] = bfu(p.x & 0xffffu); f[1] = bfu(p.x >> 16);
    f[2] = bfu(p.y & 0xffffu); f[3] = bfu(p.y >> 16);
    f[4] = bfu(p.z & 0xffffu); f[5] = bfu(p.z >> 16);
    f[6] = bfu(p.w & 0xffffu); f[7] = bfu(p.w >> 16);
}
__device__ __forceinline__ float sigm(float x) { return 1.f / (1.f + expf(-x)); }
__device__ __forceinline__ float sigm_fast(float x) { return 1.f / (1.f + __expf(-x)); }
__device__ __forceinline__ float tanh_fast(float x) {
    const float t = __expf(2.f * x);          // args bounded ~|x|<12 here: no overflow
    return (t - 1.f) / (t + 1.f);
}

// ---------------------------------------------------------------------------
// K0: gi[dir][b][s][192] = embeds[b][s] . Wih_dir^T + bih (+ bhh for gates r,z).
// No sequential dependence -> fully parallel. grid = 1024 (b, s-chunk of 64),
// block = 384 (one thread per output column: 2 dirs x 192).
// ---------------------------------------------------------------------------
__global__ __launch_bounds__(384) void gi_kernel(
    const int* __restrict__ inputs, const float* __restrict__ emb,
    const float* __restrict__ Wih_f, const float* __restrict__ bih_f,
    const float* __restrict__ bhh_f,
    const float* __restrict__ Wih_b, const float* __restrict__ bih_b,
    const float* __restrict__ bhh_b,
    float* __restrict__ gi)
{
    const int b  = blockIdx.x >> 3;
    const int s0 = (blockIdx.x & 7) << 6;
    const int tid = threadIdx.x;

    __shared__ float xs[64][E_];   // 8 KB
    __shared__ int idx[64];
    if (tid < 64) idx[tid] = inputs[b * S_ + s0 + tid];
    __syncthreads();
    for (int i = tid; i < 64 * E_; i += 384) {
        xs[i >> 5][i & 31] = emb[(unsigned)idx[i >> 5] * E_ + (i & 31)];
    }
    __syncthreads();

    const int dir = (tid >= 192) ? 1 : 0;
    const int j = tid - dir * 192;               // 0..191: gate*64 + elem
    const float* Wih = dir ? Wih_b : Wih_f;
    const float* bih = dir ? bih_b : bih_f;
    const float* bhh = dir ? bhh_b : bhh_f;

    float w[E_];
    #pragma unroll
    for (int k = 0; k < E_; k += 4)
        *(float4*)(w + k) = *(const float4*)(Wih + j * E_ + k);
    // fold both biases for r,z (j<128); only b_ih for n (b_hh[n] stays inside r*(...))
    const float c = bih[j] + (j < 128 ? bhh[j] : 0.f);

    float* gout = gi + (((size_t)(dir * B_ + b)) * S_ + s0) * 192 + j;
    for (int r = 0; r < 64; r++) {
        const float4* xr = (const float4*)xs[r];   // uniform addr -> LDS broadcast
        float a0 = 0.f, a1 = 0.f, a2 = 0.f, a3 = 0.f;
        #pragma unroll
        for (int q = 0; q < E_ / 4; q++) {
            const float4 x = xr[q];
            a0 += x.x * w[4 * q + 0]; a1 += x.y * w[4 * q + 1];
            a2 += x.z * w[4 * q + 2]; a3 += x.w * w[4 * q + 3];
        }
        gout[(size_t)r * 192] = ((a0 + a1) + (a2 + a3)) + c;   // coalesced per r
    }
}

// ---------------------------------------------------------------------------
// K1: encoder BiGRU recurrence. grid = 256 (b, dir), block = 192 = 3 waves.
// Wave g (= tid>>6) owns gate g; lane j holds row g*64+j of Whh as 16 f32x4
// (64 VGPRs -> no spill possible). Per step: each lane computes one 64-long
// dot against hs (LDS broadcast reads), folds gi / biases, writes sg; wave 0
// then applies activations, updates hs[j], stores output. 2 barriers/step.
// gi streamed from global, prefetched 2 steps ahead (one coalesced scalar
// load per wave per step; latency spans two barrier periods).
// outputs: bf16 [B][S][H]; sn: fp32 [B][H].
// ---------------------------------------------------------------------------
__global__ __launch_bounds__(192, 1) void encoder_kernel(
    const float* __restrict__ gi,
    const float* __restrict__ Whh_f, const float* __restrict__ bhh_f,
    const float* __restrict__ Whh_b, const float* __restrict__ bhh_b,
    u16* __restrict__ outputs, float* __restrict__ sn)
{
    const int tid = threadIdx.x;
    const int g = tid >> 6;                 // wave / gate 0..2
    const int j = tid & 63;                 // lane
    const int b = blockIdx.x & 127;
    const int dir = blockIdx.x >> 7;

    const float* Whh = dir ? Whh_b : Whh_f;
    const float* bhh = dir ? bhh_b : bhh_f;

    // 64 weights/lane: row (g*64+j) of Whh. 16 f32x4, constant-indexed.
    f32x4 wv[16];
    {
        const f32x4* wr = (const f32x4*)(Whh + (g * 64 + j) * 64);
        #pragma unroll
        for (int k = 0; k < 16; k++) wv[k] = wr[k];
    }
    // gate n: b_hh[128+j] is inside the r*( ) term -> fold into the gh sum
    const float badd = (g == 2) ? bhh[128 + j] : 0.f;

    __shared__ __attribute__((aligned(16))) float hs[64];
    __shared__ float sg[4 * 64];   // [0:64) r-pre, [64:128) z-pre, [128:192) gh_n+bhh, [192:256) gi_n
    if (tid < 64) hs[tid] = 0.f;
    float hmine = 0.f;             // tracked by wave 0

    const float* gp = gi + ((size_t)(dir * B_ + b)) * S_ * 192 + g * 64 + j;
    u16* orow = outputs + ((size_t)b * S_) * H_ + (dir << 6) + j;   // wave 0 only

    const int st = dir ? -1 : 1;
    int oc = dir ? (S_ - 1) : 0;

    // 2-deep gi prefetch. OOB step indices (oc +- 2) stay inside the gi
    // allocation: fwd chains overrun into the next chain's region, bwd chains
    // underrun into the previous one; values are never consumed.
    float pa = gp[(long)oc * 192];
    float pb = gp[(long)(oc + st) * 192];

#define ENC_STEP(PCUR)                                                         \
    {                                                                          \
        __syncthreads();               /* hs ready; prev sg reads retired */   \
        f32x4 acc = {0.f, 0.f, 0.f, 0.f};                                      \
        _Pragma("unroll")                                                      \
        for (int q = 0; q < 16; q++)                                           \
            acc += *(const f32x4*)(hs + 4 * q) * wv[q];                        \
        const float d = (acc[0] + acc[1]) + (acc[2] + acc[3]);                 \
        if (g == 2) { sg[128 + j] = d + badd; sg[192 + j] = PCUR; }            \
        else        { sg[g * 64 + j] = d + PCUR; }                             \
        PCUR = gp[(long)(oc + 2 * st) * 192];   /* prefetch step s+2 */        \
        __syncthreads();               /* sg ready */                          \
        if (g == 0) {                                                          \
            const float r = sigm_fast(sg[j]);                                  \
            const float z = sigm_fast(sg[64 + j]);                             \
            const float n = tanh_fast(sg[192 + j] + r * sg[128 + j]);          \
            const float hn = n + z * (hmine - n);                              \
            hmine = hn;                                                        \
            hs[j] = hn;                                                        \
            orow[(long)oc * H_] = f2bf(hn);                                    \
        }                                                                      \
        oc += st;                                                              \
    }

    for (int s = 0; s < S_; s += 2) {
        ENC_STEP(pa)
        ENC_STEP(pb)
    }
#undef ENC_STEP

    if (g == 0) sn[(b << 7) + (dir << 6) + j] = hmine;
}

// ---------------------------------------------------------------------------
// K2: t2[b][h] = sn[b] . W2[h] + b2[h].  grid=128, block=128. All fp32.
// ---------------------------------------------------------------------------
__global__ __launch_bounds__(128) void t2_kernel(
    const float* __restrict__ sn, const float* __restrict__ W2,
    const float* __restrict__ b2, float* __restrict__ t2)
{
    const int b = blockIdx.x, h = threadIdx.x;
    __shared__ float s_[H_];
    s_[h] = sn[b * H_ + h];
    __syncthreads();
    const float4* wr = (const float4*)(W2 + h * H_);
    float a0 = 0.f, a1 = 0.f, a2 = 0.f, a3 = 0.f;
    #pragma unroll 4
    for (int k = 0; k < H_ / 4; k++) {
        const float4 p = wr[k];
        a0 += s_[4 * k + 0] * p.x; a1 += s_[4 * k + 1] * p.y;
        a2 += s_[4 * k + 2] * p.z; a3 += s_[4 * k + 3] * p.w;
    }
    t2[b * H_ + h] = ((a0 + a1) + (a2 + a3)) + b2[h];
}

// ---------------------------------------------------------------------------
// K3: fp32 -> bf16 conversion (used for W1 and W_out). 4 elems/thread.
// ---------------------------------------------------------------------------
__global__ __launch_bounds__(256) void cvt_bf16_kernel(
    const float* __restrict__ src, u16* __restrict__ dst)
{
    const int i = (blockIdx.x * 256 + threadIdx.x) * 4;
    const float4 p = *(const float4*)(src + i);
    ushort4 q;
    q.x = f2bf(p.x); q.y = f2bf(p.y); q.z = f2bf(p.z); q.w = f2bf(p.w);
    *(ushort4*)(dst + i) = q;
}

// ---------------------------------------------------------------------------
// K4: gate via MFMA. pre[m][n] = outputs[m] . W1[n];
// enc[m][n] = outputs[m][n] * sigmoid(pre + b1[n] + t2[b][n]),  b = m>>9.
// M=65536 rows, N=128, K=128. Block = 4 waves, tile 64(M)x128(N). grid=1024.
// ---------------------------------------------------------------------------
__global__ __launch_bounds__(256) void gate_mfma_kernel(
    const u16* __restrict__ outputs, const u16* __restrict__ W1b,
    const float* __restrict__ b1, const float* __restrict__ t2,
    u16* __restrict__ enc)
{
    const int l = threadIdx.x & 63;
    const int w = threadIdx.x >> 6;
    const int tile_m = blockIdx.x * 64 + w * 16;
    const int row_a = tile_m + (l & 15);
    const int kb = (l >> 4) * 8;
    const int b = blockIdx.x >> 3;           // 8 blocks of 64 rows per batch

    f32x4 acc[8] = {};
    #pragma unroll
    for (int kk = 0; kk < 4; kk++) {
        const int k0 = kk * 32 + kb;
        const short8 af = *(const short8*)(outputs + row_a * H_ + k0);
        #pragma unroll
        for (int i = 0; i < 8; i++) {
            const int n = i * 16 + (l & 15);
            const short8 bv = *(const short8*)(W1b + n * H_ + k0);
            acc[i] = __builtin_amdgcn_mfma_f32_16x16x32_bf16(af, bv, acc[i], 0, 0, 0);
        }
    }

    const int m_base = tile_m + (l >> 4) * 4;
    #pragma unroll
    for (int i = 0; i < 8; i++) {
        const int n = i * 16 + (l & 15);
        const float bias = b1[n] + t2[b * H_ + n];
        #pragma unroll
        for (int r = 0; r < 4; r++) {
            const int m = m_base + r;
            const float g = sigm_fast(acc[i][r] + bias);
            const float o = bfu(outputs[m * H_ + n]);
            enc[m * H_ + n] = f2bf(o * g);
        }
    }
}

// ---------------------------------------------------------------------------
// K5: decoder. grid = 128 (one WG per batch), block = 256. 15 steps:
// attention (softmax over S=512, enc bf16) + GRU (fp32 weights).
// ---------------------------------------------------------------------------
__global__ __launch_bounds__(256) void decoder_kernel(
    const int* __restrict__ targets, const float* __restrict__ emb,
    const float* __restrict__ Wihd, const float* __restrict__ Whhd,
    const float* __restrict__ bihd, const float* __restrict__ bhhd,
    const u16* __restrict__ enc, const float* __restrict__ sn,
    u16* __restrict__ h_all)
{
    const int b = blockIdx.x;
    const int tid = threadIdx.x;
    __shared__ float h[H_];
    __shared__ float sc[S_];
    __shared__ float xv[H_ + E_];     // [c(128), e(32)]
    __shared__ float red[256];
    __shared__ float chalf[2][H_];
    __shared__ float sgi[3 * H_];
    __shared__ float sgh[3 * H_];

    if (tid < H_) h[tid] = sn[b * H_ + tid];
    __syncthreads();

    const u16* encb = enc + b * S_ * H_;

    for (int t = 0; t < TDEC; t++) {
        const int word = targets[b * 16 + t];

        // ---- pass 1: scores sc[s] = h . enc[b][s] ----
        for (int s = tid; s < S_; s += 256) {
            const u16* row = encb + s * H_;
            float a0 = 0.f, a1 = 0.f, a2 = 0.f, a3 = 0.f;
            for (int k = 0; k < H_; k += 8) {
                uint4 p = *(const uint4*)(row + k);
                float f[8]; bf8_to_f(p, f);
                a0 += h[k + 0] * f[0]; a1 += h[k + 1] * f[1];
                a2 += h[k + 2] * f[2]; a3 += h[k + 3] * f[3];
                a0 += h[k + 4] * f[4]; a1 += h[k + 5] * f[5];
                a2 += h[k + 6] * f[6]; a3 += h[k + 7] * f[7];
            }
            sc[s] = (a0 + a1) + (a2 + a3);
        }
        __syncthreads();

        // ---- softmax over 512 ----
        red[tid] = fmaxf(sc[tid], sc[tid + 256]);
        __syncthreads();
        for (int off = 128; off > 0; off >>= 1) {
            if (tid < off) red[tid] = fmaxf(red[tid], red[tid + off]);
            __syncthreads();
        }
        const float m = red[0];
        __syncthreads();
        const float e0 = expf(sc[tid] - m);
        const float e1 = expf(sc[tid + 256] - m);
        red[tid] = e0 + e1;
        __syncthreads();
        for (int off = 128; off > 0; off >>= 1) {
            if (tid < off) red[tid] = red[tid] + red[tid + off];
            __syncthreads();
        }
        const float inv = 1.f / red[0];
        __syncthreads();
        sc[tid] = e0 * inv;
        sc[tid + 256] = e1 * inv;
        __syncthreads();

        // ---- pass 2: c[k] = sum_s alpha[s] * enc[b][s][k] ----
        {
            const int k = tid & 127;
            const int half = tid >> 7;
            const u16* basep = encb + (half * 256) * H_ + k;
            const float* al = sc + half * 256;
            float c0 = 0.f, c1 = 0.f, c2 = 0.f, c3 = 0.f;
            for (int s = 0; s < 256; s += 4) {
                c0 += al[s + 0] * bfu(basep[(s + 0) * H_]);
                c1 += al[s + 1] * bfu(basep[(s + 1) * H_]);
                c2 += al[s + 2] * bfu(basep[(s + 2) * H_]);
                c3 += al[s + 3] * bfu(basep[(s + 3) * H_]);
            }
            chalf[half][k] = (c0 + c1) + (c2 + c3);
        }
        __syncthreads();
        if (tid < H_) xv[tid] = chalf[0][tid] + chalf[1][tid];
        else if (tid < H_ + E_) xv[tid] = emb[(unsigned)word * E_ + (tid - H_)];
        __syncthreads();

        // ---- gates ----
        for (int j = tid; j < 3 * H_; j += 256) {
            const float4* wr = (const float4*)(Wihd + j * (H_ + E_));
            float a0 = 0.f, a1 = 0.f, a2 = 0.f, a3 = 0.f;
            for (int k = 0; k < (H_ + E_) / 4; k++) {
                const float4 p = wr[k];
                a0 += xv[4 * k + 0] * p.x; a1 += xv[4 * k + 1] * p.y;
                a2 += xv[4 * k + 2] * p.z; a3 += xv[4 * k + 3] * p.w;
            }
            sgi[j] = ((a0 + a1) + (a2 + a3)) + bihd[j];

            const float4* hr = (const float4*)(Whhd + j * H_);
            float b0 = 0.f, b1_ = 0.f, b2_ = 0.f, b3 = 0.f;
            for (int k = 0; k < H_ / 4; k++) {
                const float4 p = hr[k];
                b0  += h[4 * k + 0] * p.x; b1_ += h[4 * k + 1] * p.y;
                b2_ += h[4 * k + 2] * p.z; b3  += h[4 * k + 3] * p.w;
            }
            sgh[j] = ((b0 + b1_) + (b2_ + b3)) + bhhd[j];
        }
        __syncthreads();

        if (tid < H_) {
            const float r = sigm(sgi[tid] + sgh[tid]);
            const float z = sigm(sgi[H_ + tid] + sgh[H_ + tid]);
            const float n = tanhf(sgi[2 * H_ + tid] + r * sgh[2 * H_ + tid]);
            const float hn = (1.f - z) * n + z * h[tid];
            h[tid] = hn;
            h_all[(t * B_ + b) * H_ + tid] = f2bf(hn);
        }
        __syncthreads();
    }
}

// ---------------------------------------------------------------------------
// K6: logits = h_all @ Woutb^T + b_out. MFMA bf16 NT GEMM, fp32 out.
// M=1920 (t*128+b), N=32000, K=128. grid=(500,30), block=256.
// Output: out[(b*15 + t)*32000 + n], fp32.
// ---------------------------------------------------------------------------
__global__ __launch_bounds__(256) void logits_kernel(
    const u16* __restrict__ hall, const u16* __restrict__ Woutb,
    const float* __restrict__ bout, float* __restrict__ out)
{
    const int l = threadIdx.x & 63;
    const int w = threadIdx.x >> 6;
    const int tile_n = blockIdx.x * 64;
    const int tile_m = blockIdx.y * 64 + w * 16;

    f32x4 acc[4] = {};
    const int row_a = tile_m + (l & 15);
    const int kb = (l >> 4) * 8;

    #pragma unroll
    for (int kk = 0; kk < 4; kk++) {
        const int k0 = kk * 32 + kb;
        const short8 af = *(const short8*)(hall + row_a * H_ + k0);
        #pragma unroll
        for (int i = 0; i < 4; i++) {
            const int n = tile_n + i * 16 + (l & 15);
            const short8 bv = *(const short8*)(Woutb + n * H_ + k0);
            acc[i] = __builtin_amdgcn_mfma_f32_16x16x32_bf16(af, bv, acc[i], 0, 0, 0);
        }
    }

    const int m_base = tile_m + (l >> 4) * 4;
    #pragma unroll
    for (int i = 0; i < 4; i++) {
        const int n = tile_n + i * 16 + (l & 15);
        const float bias = bout[n];
        #pragma unroll
        for (int r = 0; r < 4; r++) {
            const int m = m_base + r;
            const int t = m >> 7;
            const int bb = m & 127;
            out[(size_t)(bb * TDEC + t) * V_ + n] = acc[i][r] + bias;
        }
    }
}

// ---------------------------------------------------------------------------
extern "C" void kernel_launch(void* const* d_in, const int* in_sizes, int n_in,
                              void* d_out, int out_size, void* d_ws, size_t ws_size,
                              hipStream_t stream) {
    const int*   inputs  = (const int*)d_in[0];
    const int*   targets = (const int*)d_in[1];
    const float* emb     = (const float*)d_in[2];
    const float* Wih_f   = (const float*)d_in[3];
    const float* Whh_f   = (const float*)d_in[4];
    const float* bih_f   = (const float*)d_in[5];
    const float* bhh_f   = (const float*)d_in[6];
    const float* Wih_b   = (const float*)d_in[7];
    const float* Whh_b   = (const float*)d_in[8];
    const float* bih_b   = (const float*)d_in[9];
    const float* bhh_b   = (const float*)d_in[10];
    const float* W1      = (const float*)d_in[11];
    const float* b1      = (const float*)d_in[12];
    const float* W2      = (const float*)d_in[13];
    const float* b2      = (const float*)d_in[14];
    const float* Wihd    = (const float*)d_in[15];
    const float* Whhd    = (const float*)d_in[16];
    const float* bihd    = (const float*)d_in[17];
    const float* bhhd    = (const float*)d_in[18];
    const float* Wout    = (const float*)d_in[19];
    const float* bout    = (const float*)d_in[20];
    float* out = (float*)d_out;

    // Staging at the front of d_out (245.76 MB). The logits kernel runs last
    // and overwrites every element of d_out with the real output.
    u16*   outputs = (u16*)d_out;                       // bf16 B*S*H = 16,777,216 B
    u16*   enc     = (u16*)((char*)d_out + 16777216);   // bf16 B*S*H = 16,777,216 B
    u16*   W1b     = (u16*)((char*)d_out + 33554432);   // bf16 H*H   =     32,768 B
    float* gi      = (float*)((char*)d_out + 33619968); // f32 2*B*S*192 = 100,663,296 B (ends @134MB < 245MB)

    // d_ws: small state only (8.82 MB total) — layout validated in R3.
    char* ws = (char*)d_ws;
    float* sn    = (float*)(ws);                 // B*H  f32    =  65,536 B
    float* t2    = (float*)(ws + 65536);         // B*H  f32    =  65,536 B
    u16*   h_all = (u16*)(ws + 131072);          // 15*B*H bf16 = 491,520 B
    u16*   Woutb = (u16*)(ws + 622592);          // V*H bf16    = 8,192,000 B

    gi_kernel<<<B_ * (S_ / 64), 384, 0, stream>>>(inputs, emb, Wih_f, bih_f, bhh_f,
                                                  Wih_b, bih_b, bhh_b, gi);
    encoder_kernel<<<256, 192, 0, stream>>>(gi, Whh_f, bhh_f, Whh_b, bhh_b, outputs, sn);
    t2_kernel<<<128, 128, 0, stream>>>(sn, W2, b2, t2);
    cvt_bf16_kernel<<<H_ * H_ / 1024, 256, 0, stream>>>(W1, W1b);
    cvt_bf16_kernel<<<V_ * H_ / 1024, 256, 0, stream>>>(Wout, Woutb);
    gate_mfma_kernel<<<B_ * S_ / 64, 256, 0, stream>>>(outputs, W1b, b1, t2, enc);
    decoder_kernel<<<128, 256, 0, stream>>>(targets, emb, Wihd, Whhd, bihd, bhhd,
                                            enc, sn, h_all);
    logits_kernel<<<dim3(500, 30), 256, 0, stream>>>(h_all, Woutb, bout, out);
}

// Round 6
// 971.963 us; speedup vs baseline: 1.9125x; 1.0724x over previous
//
#include <hip/hip_runtime.h>
#include <hip/hip_bf16.h>

// Model: BiGRU encoder (B=128, S=512, E=32, Hh=64) + gated enc_outs +
// 15-step attention GRU decoder (H=128) + logits GEMM (1920x32000x128).
// fp32 inputs/outputs; bf16 internal staging (outputs, enc, h_all, W1b, Woutb).
//
// R10: decoder is now the top kernel (340us, VALUBusy 7.8%, occ 5.9% ->
//      latency-bound, ~20 barriers/step, 2-row serial chains per thread).
//      Rewritten with 512 threads (8 waves): 1 enc row/thread in pass 1,
//      shuffle-based softmax (3 barriers instead of 16), 4-way split pass 2,
//      1 gate row/thread (384 of 512), 7 barriers/step total.
//      Encoder (R9 3-wave split), gi, gate_mfma, logits unchanged.

typedef unsigned short u16;
typedef unsigned int u32;
typedef __attribute__((ext_vector_type(8))) short short8;
typedef __attribute__((ext_vector_type(4))) float f32x4;

#define V_ 32000
#define E_ 32
#define H_ 128
#define B_ 128
#define S_ 512
#define TDEC 15   // T-1

__device__ __forceinline__ float bfu(u32 u) {
    union { u32 i; float f; } v; v.i = u << 16; return v.f;
}
__device__ __forceinline__ u16 f2bf(float f) {
    union { float f; u32 i; } v; v.f = f;
    u32 x = v.i;
    u32 r = (x + 0x7fffu + ((x >> 16) & 1u)) >> 16;
    return (u16)r;
}
__device__ __forceinline__ void bf8_to_f(const uint4 p, float* f) {
    f[0] = bfu(p.x & 0xffffu); f[1] = bfu(p.x >> 16);
    f[2] = bfu(p.y & 0xffffu); f[3] = bfu(p.y >> 16);
    f[4] = bfu(p.z & 0xffffu); f[5] = bfu(p.z >> 16);
    f[6] = bfu(p.w & 0xffffu); f[7] = bfu(p.w >> 16);
}
__device__ __forceinline__ float sigm(float x) { return 1.f / (1.f + expf(-x)); }
__device__ __forceinline__ float sigm_fast(float x) { return 1.f / (1.f + __expf(-x)); }
__device__ __forceinline__ float tanh_fast(float x) {
    const float t = __expf(2.f * x);          // args bounded ~|x|<12 here: no overflow
    return (t - 1.f) / (t + 1.f);
}

// ---------------------------------------------------------------------------
// K0: gi[dir][b][s][192] = embeds[b][s] . Wih_dir^T + bih (+ bhh for gates r,z).
// No sequential dependence -> fully parallel. grid = 1024 (b, s-chunk of 64),
// block = 384 (one thread per output column: 2 dirs x 192).
// ---------------------------------------------------------------------------
__global__ __launch_bounds__(384) void gi_kernel(
    const int* __restrict__ inputs, const float* __restrict__ emb,
    const float* __restrict__ Wih_f, const float* __restrict__ bih_f,
    const float* __restrict__ bhh_f,
    const float* __restrict__ Wih_b, const float* __restrict__ bih_b,
    const float* __restrict__ bhh_b,
    float* __restrict__ gi)
{
    const int b  = blockIdx.x >> 3;
    const int s0 = (blockIdx.x & 7) << 6;
    const int tid = threadIdx.x;

    __shared__ float xs[64][E_];   // 8 KB
    __shared__ int idx[64];
    if (tid < 64) idx[tid] = inputs[b * S_ + s0 + tid];
    __syncthreads();
    for (int i = tid; i < 64 * E_; i += 384) {
        xs[i >> 5][i & 31] = emb[(unsigned)idx[i >> 5] * E_ + (i & 31)];
    }
    __syncthreads();

    const int dir = (tid >= 192) ? 1 : 0;
    const int j = tid - dir * 192;               // 0..191: gate*64 + elem
    const float* Wih = dir ? Wih_b : Wih_f;
    const float* bih = dir ? bih_b : bih_f;
    const float* bhh = dir ? bhh_b : bhh_f;

    float w[E_];
    #pragma unroll
    for (int k = 0; k < E_; k += 4)
        *(float4*)(w + k) = *(const float4*)(Wih + j * E_ + k);
    // fold both biases for r,z (j<128); only b_ih for n (b_hh[n] stays inside r*(...))
    const float c = bih[j] + (j < 128 ? bhh[j] : 0.f);

    float* gout = gi + (((size_t)(dir * B_ + b)) * S_ + s0) * 192 + j;
    for (int r = 0; r < 64; r++) {
        const float4* xr = (const float4*)xs[r];   // uniform addr -> LDS broadcast
        float a0 = 0.f, a1 = 0.f, a2 = 0.f, a3 = 0.f;
        #pragma unroll
        for (int q = 0; q < E_ / 4; q++) {
            const float4 x = xr[q];
            a0 += x.x * w[4 * q + 0]; a1 += x.y * w[4 * q + 1];
            a2 += x.z * w[4 * q + 2]; a3 += x.w * w[4 * q + 3];
        }
        gout[(size_t)r * 192] = ((a0 + a1) + (a2 + a3)) + c;   // coalesced per r
    }
}

// ---------------------------------------------------------------------------
// K1: encoder BiGRU recurrence. grid = 256 (b, dir), block = 192 = 3 waves.
// Wave g (= tid>>6) owns gate g; lane j holds row g*64+j of Whh as 16 f32x4
// (64 VGPRs -> no spill possible). Per step: each lane computes one 64-long
// dot against hs (LDS broadcast reads), folds gi / biases, writes sg; wave 0
// then applies activations, updates hs[j], stores output. 2 barriers/step.
// gi streamed from global, prefetched 2 steps ahead.
// outputs: bf16 [B][S][H]; sn: fp32 [B][H].
// ---------------------------------------------------------------------------
__global__ __launch_bounds__(192, 1) void encoder_kernel(
    const float* __restrict__ gi,
    const float* __restrict__ Whh_f, const float* __restrict__ bhh_f,
    const float* __restrict__ Whh_b, const float* __restrict__ bhh_b,
    u16* __restrict__ outputs, float* __restrict__ sn)
{
    const int tid = threadIdx.x;
    const int g = tid >> 6;                 // wave / gate 0..2
    const int j = tid & 63;                 // lane
    const int b = blockIdx.x & 127;
    const int dir = blockIdx.x >> 7;

    const float* Whh = dir ? Whh_b : Whh_f;
    const float* bhh = dir ? bhh_b : bhh_f;

    // 64 weights/lane: row (g*64+j) of Whh. 16 f32x4, constant-indexed.
    f32x4 wv[16];
    {
        const f32x4* wr = (const f32x4*)(Whh + (g * 64 + j) * 64);
        #pragma unroll
        for (int k = 0; k < 16; k++) wv[k] = wr[k];
    }
    // gate n: b_hh[128+j] is inside the r*( ) term -> fold into the gh sum
    const float badd = (g == 2) ? bhh[128 + j] : 0.f;

    __shared__ __attribute__((aligned(16))) float hs[64];
    __shared__ float sg[4 * 64];   // [0:64) r-pre, [64:128) z-pre, [128:192) gh_n+bhh, [192:256) gi_n
    if (tid < 64) hs[tid] = 0.f;
    float hmine = 0.f;             // tracked by wave 0

    const float* gp = gi + ((size_t)(dir * B_ + b)) * S_ * 192 + g * 64 + j;
    u16* orow = outputs + ((size_t)b * S_) * H_ + (dir << 6) + j;   // wave 0 only

    const int st = dir ? -1 : 1;
    int oc = dir ? (S_ - 1) : 0;

    // 2-deep gi prefetch. OOB step indices (oc +- 2) stay inside the gi
    // allocation; values are never consumed.
    float pa = gp[(long)oc * 192];
    float pb = gp[(long)(oc + st) * 192];

#define ENC_STEP(PCUR)                                                         \
    {                                                                          \
        __syncthreads();               /* hs ready; prev sg reads retired */   \
        f32x4 acc = {0.f, 0.f, 0.f, 0.f};                                      \
        _Pragma("unroll")                                                      \
        for (int q = 0; q < 16; q++)                                           \
            acc += *(const f32x4*)(hs + 4 * q) * wv[q];                        \
        const float d = (acc[0] + acc[1]) + (acc[2] + acc[3]);                 \
        if (g == 2) { sg[128 + j] = d + badd; sg[192 + j] = PCUR; }            \
        else        { sg[g * 64 + j] = d + PCUR; }                             \
        PCUR = gp[(long)(oc + 2 * st) * 192];   /* prefetch step s+2 */        \
        __syncthreads();               /* sg ready */                          \
        if (g == 0) {                                                          \
            const float r = sigm_fast(sg[j]);                                  \
            const float z = sigm_fast(sg[64 + j]);                             \
            const float n = tanh_fast(sg[192 + j] + r * sg[128 + j]);          \
            const float hn = n + z * (hmine - n);                              \
            hmine = hn;                                                        \
            hs[j] = hn;                                                        \
            orow[(long)oc * H_] = f2bf(hn);                                    \
        }                                                                      \
        oc += st;                                                              \
    }

    for (int s = 0; s < S_; s += 2) {
        ENC_STEP(pa)
        ENC_STEP(pb)
    }
#undef ENC_STEP

    if (g == 0) sn[(b << 7) + (dir << 6) + j] = hmine;
}

// ---------------------------------------------------------------------------
// K2: t2[b][h] = sn[b] . W2[h] + b2[h].  grid=128, block=128. All fp32.
// ---------------------------------------------------------------------------
__global__ __launch_bounds__(128) void t2_kernel(
    const float* __restrict__ sn, const float* __restrict__ W2,
    const float* __restrict__ b2, float* __restrict__ t2)
{
    const int b = blockIdx.x, h = threadIdx.x;
    __shared__ float s_[H_];
    s_[h] = sn[b * H_ + h];
    __syncthreads();
    const float4* wr = (const float4*)(W2 + h * H_);
    float a0 = 0.f, a1 = 0.f, a2 = 0.f, a3 = 0.f;
    #pragma unroll 4
    for (int k = 0; k < H_ / 4; k++) {
        const float4 p = wr[k];
        a0 += s_[4 * k + 0] * p.x; a1 += s_[4 * k + 1] * p.y;
        a2 += s_[4 * k + 2] * p.z; a3 += s_[4 * k + 3] * p.w;
    }
    t2[b * H_ + h] = ((a0 + a1) + (a2 + a3)) + b2[h];
}

// ---------------------------------------------------------------------------
// K3: fp32 -> bf16 conversion (used for W1 and W_out). 4 elems/thread.
// ---------------------------------------------------------------------------
__global__ __launch_bounds__(256) void cvt_bf16_kernel(
    const float* __restrict__ src, u16* __restrict__ dst)
{
    const int i = (blockIdx.x * 256 + threadIdx.x) * 4;
    const float4 p = *(const float4*)(src + i);
    ushort4 q;
    q.x = f2bf(p.x); q.y = f2bf(p.y); q.z = f2bf(p.z); q.w = f2bf(p.w);
    *(ushort4*)(dst + i) = q;
}

// ---------------------------------------------------------------------------
// K4: gate via MFMA. pre[m][n] = outputs[m] . W1[n];
// enc[m][n] = outputs[m][n] * sigmoid(pre + b1[n] + t2[b][n]),  b = m>>9.
// M=65536 rows, N=128, K=128. Block = 4 waves, tile 64(M)x128(N). grid=1024.
// ---------------------------------------------------------------------------
__global__ __launch_bounds__(256) void gate_mfma_kernel(
    const u16* __restrict__ outputs, const u16* __restrict__ W1b,
    const float* __restrict__ b1, const float* __restrict__ t2,
    u16* __restrict__ enc)
{
    const int l = threadIdx.x & 63;
    const int w = threadIdx.x >> 6;
    const int tile_m = blockIdx.x * 64 + w * 16;
    const int row_a = tile_m + (l & 15);
    const int kb = (l >> 4) * 8;
    const int b = blockIdx.x >> 3;           // 8 blocks of 64 rows per batch

    f32x4 acc[8] = {};
    #pragma unroll
    for (int kk = 0; kk < 4; kk++) {
        const int k0 = kk * 32 + kb;
        const short8 af = *(const short8*)(outputs + row_a * H_ + k0);
        #pragma unroll
        for (int i = 0; i < 8; i++) {
            const int n = i * 16 + (l & 15);
            const short8 bv = *(const short8*)(W1b + n * H_ + k0);
            acc[i] = __builtin_amdgcn_mfma_f32_16x16x32_bf16(af, bv, acc[i], 0, 0, 0);
        }
    }

    const int m_base = tile_m + (l >> 4) * 4;
    #pragma unroll
    for (int i = 0; i < 8; i++) {
        const int n = i * 16 + (l & 15);
        const float bias = b1[n] + t2[b * H_ + n];
        #pragma unroll
        for (int r = 0; r < 4; r++) {
            const int m = m_base + r;
            const float g = sigm_fast(acc[i][r] + bias);
            const float o = bfu(outputs[m * H_ + n]);
            enc[m * H_ + n] = f2bf(o * g);
        }
    }
}

// ---------------------------------------------------------------------------
// K5: decoder. grid = 128 (one WG per batch), block = 512 = 8 waves. 15 steps:
// attention (softmax over S=512, enc bf16) + GRU (fp32 weights).
// pass1: 1 enc row per thread. softmax: wave shuffle reduce + 8-entry combine
// (3 barriers). pass2: 4-way s-split. gates: 1 row per thread (384 of 512).
// 7 barriers/step total.
// ---------------------------------------------------------------------------
__global__ __launch_bounds__(512) void decoder_kernel(
    const int* __restrict__ targets, const float* __restrict__ emb,
    const float* __restrict__ Wihd, const float* __restrict__ Whhd,
    const float* __restrict__ bihd, const float* __restrict__ bhhd,
    const u16* __restrict__ enc, const float* __restrict__ sn,
    u16* __restrict__ h_all)
{
    const int b = blockIdx.x;
    const int tid = threadIdx.x;
    const int lane = tid & 63;
    const int wid = tid >> 6;                 // 0..7

    __shared__ __attribute__((aligned(16))) float h[H_];
    __shared__ float sc[S_];
    __shared__ float xv[H_ + E_];             // [c(128), e(32)]
    __shared__ float redm[8], reds[8];
    __shared__ float cpart[4][H_];
    __shared__ float sgi[3 * H_];
    __shared__ float sgh[3 * H_];

    if (tid < H_) h[tid] = sn[b * H_ + tid];
    __syncthreads();

    const u16* encb = enc + b * S_ * H_;

    for (int t = 0; t < TDEC; t++) {
        const int word = targets[b * 16 + t];

        // ---- pass 1: score d = h . enc[b][tid], one row per thread ----
        const u16* row = encb + tid * H_;
        float a0 = 0.f, a1 = 0.f, a2 = 0.f, a3 = 0.f;
        #pragma unroll
        for (int k = 0; k < H_; k += 8) {
            uint4 p = *(const uint4*)(row + k);
            float f[8]; bf8_to_f(p, f);
            const f32x4 h0 = *(const f32x4*)(h + k);
            const f32x4 h1 = *(const f32x4*)(h + k + 4);
            a0 += h0[0] * f[0]; a1 += h0[1] * f[1];
            a2 += h0[2] * f[2]; a3 += h0[3] * f[3];
            a0 += h1[0] * f[4]; a1 += h1[1] * f[5];
            a2 += h1[2] * f[6]; a3 += h1[3] * f[7];
        }
        const float d = (a0 + a1) + (a2 + a3);

        // ---- softmax over 512: wave shuffle reduce + cross-wave combine ----
        float m = d;
        #pragma unroll
        for (int off = 32; off > 0; off >>= 1) m = fmaxf(m, __shfl_xor(m, off));
        if (lane == 0) redm[wid] = m;
        __syncthreads();                                   // B1
        float bm = redm[0];
        #pragma unroll
        for (int i = 1; i < 8; i++) bm = fmaxf(bm, redm[i]);
        const float e = expf(d - bm);
        float ssum = e;
        #pragma unroll
        for (int off = 32; off > 0; off >>= 1) ssum += __shfl_xor(ssum, off);
        if (lane == 0) reds[wid] = ssum;
        __syncthreads();                                   // B2
        float tot = reds[0];
        #pragma unroll
        for (int i = 1; i < 8; i++) tot += reds[i];
        sc[tid] = e * (1.f / tot);
        __syncthreads();                                   // B3

        // ---- pass 2: c[k] = sum_s alpha[s] enc[b][s][k], 4-way s-split ----
        {
            const int k = tid & 127;
            const int q = tid >> 7;                        // 0..3
            const u16* basep = encb + (q * 128) * H_ + k;
            const float* al = sc + q * 128;
            float c0 = 0.f, c1 = 0.f, c2 = 0.f, c3 = 0.f;
            #pragma unroll 8
            for (int s = 0; s < 128; s += 4) {
                c0 += al[s + 0] * bfu(basep[(s + 0) * H_]);
                c1 += al[s + 1] * bfu(basep[(s + 1) * H_]);
                c2 += al[s + 2] * bfu(basep[(s + 2) * H_]);
                c3 += al[s + 3] * bfu(basep[(s + 3) * H_]);
            }
            cpart[q][k] = (c0 + c1) + (c2 + c3);
        }
        __syncthreads();                                   // B4
        if (tid < H_) xv[tid] = (cpart[0][tid] + cpart[1][tid]) + (cpart[2][tid] + cpart[3][tid]);
        else if (tid < H_ + E_) xv[tid] = emb[(unsigned)word * E_ + (tid - H_)];
        __syncthreads();                                   // B5

        // ---- gates: one row per thread (tid < 384) ----
        if (tid < 3 * H_) {
            const int j = tid;
            const float4* wr = (const float4*)(Wihd + j * (H_ + E_));
            float g0 = 0.f, g1 = 0.f, g2 = 0.f, g3 = 0.f;
            #pragma unroll 8
            for (int k = 0; k < (H_ + E_) / 4; k++) {
                const float4 p = wr[k];
                g0 += xv[4 * k + 0] * p.x; g1 += xv[4 * k + 1] * p.y;
                g2 += xv[4 * k + 2] * p.z; g3 += xv[4 * k + 3] * p.w;
            }
            sgi[j] = ((g0 + g1) + (g2 + g3)) + bihd[j];

            const float4* hr = (const float4*)(Whhd + j * H_);
            float b0 = 0.f, b1_ = 0.f, b2_ = 0.f, b3 = 0.f;
            #pragma unroll 8
            for (int k = 0; k < H_ / 4; k++) {
                const float4 p = hr[k];
                b0  += h[4 * k + 0] * p.x; b1_ += h[4 * k + 1] * p.y;
                b2_ += h[4 * k + 2] * p.z; b3  += h[4 * k + 3] * p.w;
            }
            sgh[j] = ((b0 + b1_) + (b2_ + b3)) + bhhd[j];
        }
        __syncthreads();                                   // B6

        if (tid < H_) {
            const float r = sigm(sgi[tid] + sgh[tid]);
            const float z = sigm(sgi[H_ + tid] + sgh[H_ + tid]);
            const float n = tanhf(sgi[2 * H_ + tid] + r * sgh[2 * H_ + tid]);
            const float hn = (1.f - z) * n + z * h[tid];
            h[tid] = hn;
            h_all[(t * B_ + b) * H_ + tid] = f2bf(hn);
        }
        __syncthreads();                                   // B7
    }
}

// ---------------------------------------------------------------------------
// K6: logits = h_all @ Woutb^T + b_out. MFMA bf16 NT GEMM, fp32 out.
// M=1920 (t*128+b), N=32000, K=128. grid=(500,30), block=256.
// Output: out[(b*15 + t)*32000 + n], fp32.
// ---------------------------------------------------------------------------
__global__ __launch_bounds__(256) void logits_kernel(
    const u16* __restrict__ hall, const u16* __restrict__ Woutb,
    const float* __restrict__ bout, float* __restrict__ out)
{
    const int l = threadIdx.x & 63;
    const int w = threadIdx.x >> 6;
    const int tile_n = blockIdx.x * 64;
    const int tile_m = blockIdx.y * 64 + w * 16;

    f32x4 acc[4] = {};
    const int row_a = tile_m + (l & 15);
    const int kb = (l >> 4) * 8;

    #pragma unroll
    for (int kk = 0; kk < 4; kk++) {
        const int k0 = kk * 32 + kb;
        const short8 af = *(const short8*)(hall + row_a * H_ + k0);
        #pragma unroll
        for (int i = 0; i < 4; i++) {
            const int n = tile_n + i * 16 + (l & 15);
            const short8 bv = *(const short8*)(Woutb + n * H_ + k0);
            acc[i] = __builtin_amdgcn_mfma_f32_16x16x32_bf16(af, bv, acc[i], 0, 0, 0);
        }
    }

    const int m_base = tile_m + (l >> 4) * 4;
    #pragma unroll
    for (int i = 0; i < 4; i++) {
        const int n = tile_n + i * 16 + (l & 15);
        const float bias = bout[n];
        #pragma unroll
        for (int r = 0; r < 4; r++) {
            const int m = m_base + r;
            const int t = m >> 7;
            const int bb = m & 127;
            out[(size_t)(bb * TDEC + t) * V_ + n] = acc[i][r] + bias;
        }
    }
}

// ---------------------------------------------------------------------------
extern "C" void kernel_launch(void* const* d_in, const int* in_sizes, int n_in,
                              void* d_out, int out_size, void* d_ws, size_t ws_size,
                              hipStream_t stream) {
    const int*   inputs  = (const int*)d_in[0];
    const int*   targets = (const int*)d_in[1];
    const float* emb     = (const float*)d_in[2];
    const float* Wih_f   = (const float*)d_in[3];
    const float* Whh_f   = (const float*)d_in[4];
    const float* bih_f   = (const float*)d_in[5];
    const float* bhh_f   = (const float*)d_in[6];
    const float* Wih_b   = (const float*)d_in[7];
    const float* Whh_b   = (const float*)d_in[8];
    const float* bih_b   = (const float*)d_in[9];
    const float* bhh_b   = (const float*)d_in[10];
    const float* W1      = (const float*)d_in[11];
    const float* b1      = (const float*)d_in[12];
    const float* W2      = (const float*)d_in[13];
    const float* b2      = (const float*)d_in[14];
    const float* Wihd    = (const float*)d_in[15];
    const float* Whhd    = (const float*)d_in[16];
    const float* bihd    = (const float*)d_in[17];
    const float* bhhd    = (const float*)d_in[18];
    const float* Wout    = (const float*)d_in[19];
    const float* bout    = (const float*)d_in[20];
    float* out = (float*)d_out;

    // Staging at the front of d_out (245.76 MB). The logits kernel runs last
    // and overwrites every element of d_out with the real output.
    u16*   outputs = (u16*)d_out;                       // bf16 B*S*H = 16,777,216 B
    u16*   enc     = (u16*)((char*)d_out + 16777216);   // bf16 B*S*H = 16,777,216 B
    u16*   W1b     = (u16*)((char*)d_out + 33554432);   // bf16 H*H   =     32,768 B
    float* gi      = (float*)((char*)d_out + 33619968); // f32 2*B*S*192 = 100,663,296 B (ends @134MB < 245MB)

    // d_ws: small state only (8.82 MB total) — layout validated in R3.
    char* ws = (char*)d_ws;
    float* sn    = (float*)(ws);                 // B*H  f32    =  65,536 B
    float* t2    = (float*)(ws + 65536);         // B*H  f32    =  65,536 B
    u16*   h_all = (u16*)(ws + 131072);          // 15*B*H bf16 = 491,520 B
    u16*   Woutb = (u16*)(ws + 622592);          // V*H bf16    = 8,192,000 B

    gi_kernel<<<B_ * (S_ / 64), 384, 0, stream>>>(inputs, emb, Wih_f, bih_f, bhh_f,
                                                  Wih_b, bih_b, bhh_b, gi);
    encoder_kernel<<<256, 192, 0, stream>>>(gi, Whh_f, bhh_f, Whh_b, bhh_b, outputs, sn);
    t2_kernel<<<128, 128, 0, stream>>>(sn, W2, b2, t2);
    cvt_bf16_kernel<<<H_ * H_ / 1024, 256, 0, stream>>>(W1, W1b);
    cvt_bf16_kernel<<<V_ * H_ / 1024, 256, 0, stream>>>(Wout, Woutb);
    gate_mfma_kernel<<<B_ * S_ / 64, 256, 0, stream>>>(outputs, W1b, b1, t2, enc);
    decoder_kernel<<<128, 512, 0, stream>>>(targets, emb, Wihd, Whhd, bihd, bhhd,
                                            enc, sn, h_all);
    logits_kernel<<<dim3(500, 30), 256, 0, stream>>>(h_all, Woutb, bout, out);
}

// Round 7
// 949.420 us; speedup vs baseline: 1.9579x; 1.0237x over previous
//
#include <hip/hip_runtime.h>
#include <hip/hip_bf16.h>

// Model: BiGRU encoder (B=128, S=512, E=32, Hh=64) + gated enc_outs +
// 15-step attention GRU decoder (H=128) + logits GEMM (1920x32000x128).
// fp32 inputs/outputs; bf16 internal staging (outputs, enc, h_all, W1b, Woutb).
//
// R11: decoder FETCH_SIZE 96MB/dispatch @ 4.6% HBM = L2 capacity thrash
//      (16 blocks/XCD x 256KB enc + 442KB weights > 4MB L2/XCD); enc slice
//      re-streamed twice/step from a thrashing L2 with 2 waves/SIMD ->
//      latency dominated. Fix: stage the batch's enc slice (128KB bf16) in
//      LDS ONCE before the 15-step loop, with 16B-chunk XOR swizzle
//      (pos = c ^ (s&15)) for uniform bank spread on row reads (pass1) and
//      column-slice reads (pass2). Pass2 re-vectorized: 8k-chunk x 16s per
//      thread (16 x ds_read_b128), 32-partition LDS tree reduce.
//      L2 then serves only the 442KB gate weights -> clean hits.

typedef unsigned short u16;
typedef unsigned int u32;
typedef __attribute__((ext_vector_type(8))) short short8;
typedef __attribute__((ext_vector_type(4))) float f32x4;

#define V_ 32000
#define E_ 32
#define H_ 128
#define B_ 128
#define S_ 512
#define TDEC 15   // T-1

__device__ __forceinline__ float bfu(u32 u) {
    union { u32 i; float f; } v; v.i = u << 16; return v.f;
}
__device__ __forceinline__ u16 f2bf(float f) {
    union { float f; u32 i; } v; v.f = f;
    u32 x = v.i;
    u32 r = (x + 0x7fffu + ((x >> 16) & 1u)) >> 16;
    return (u16)r;
}
__device__ __forceinline__ void bf8_to_f(const uint4 p, float* f) {
    f[0] = bfu(p.x & 0xffffu); f[1] = bfu(p.x >> 16);
    f[2] = bfu(p.y & 0xffffu); f[3] = bfu(p.y >> 16);
    f[4] = bfu(p.z & 0xffffu); f[5] = bfu(p.z >> 16);
    f[6] = bfu(p.w & 0xffffu); f[7] = bfu(p.w >> 16);
}
__device__ __forceinline__ float sigm(float x) { return 1.f / (1.f + expf(-x)); }
__device__ __forceinline__ float sigm_fast(float x) { return 1.f / (1.f + __expf(-x)); }
__device__ __forceinline__ float tanh_fast(float x) {
    const float t = __expf(2.f * x);          // args bounded ~|x|<12 here: no overflow
    return (t - 1.f) / (t + 1.f);
}

// ---------------------------------------------------------------------------
// K0: gi[dir][b][s][192] = embeds[b][s] . Wih_dir^T + bih (+ bhh for gates r,z).
// No sequential dependence -> fully parallel. grid = 1024 (b, s-chunk of 64),
// block = 384 (one thread per output column: 2 dirs x 192).
// ---------------------------------------------------------------------------
__global__ __launch_bounds__(384) void gi_kernel(
    const int* __restrict__ inputs, const float* __restrict__ emb,
    const float* __restrict__ Wih_f, const float* __restrict__ bih_f,
    const float* __restrict__ bhh_f,
    const float* __restrict__ Wih_b, const float* __restrict__ bih_b,
    const float* __restrict__ bhh_b,
    float* __restrict__ gi)
{
    const int b  = blockIdx.x >> 3;
    const int s0 = (blockIdx.x & 7) << 6;
    const int tid = threadIdx.x;

    __shared__ float xs[64][E_];   // 8 KB
    __shared__ int idx[64];
    if (tid < 64) idx[tid] = inputs[b * S_ + s0 + tid];
    __syncthreads();
    for (int i = tid; i < 64 * E_; i += 384) {
        xs[i >> 5][i & 31] = emb[(unsigned)idx[i >> 5] * E_ + (i & 31)];
    }
    __syncthreads();

    const int dir = (tid >= 192) ? 1 : 0;
    const int j = tid - dir * 192;               // 0..191: gate*64 + elem
    const float* Wih = dir ? Wih_b : Wih_f;
    const float* bih = dir ? bih_b : bih_f;
    const float* bhh = dir ? bhh_b : bhh_f;

    float w[E_];
    #pragma unroll
    for (int k = 0; k < E_; k += 4)
        *(float4*)(w + k) = *(const float4*)(Wih + j * E_ + k);
    // fold both biases for r,z (j<128); only b_ih for n (b_hh[n] stays inside r*(...))
    const float c = bih[j] + (j < 128 ? bhh[j] : 0.f);

    float* gout = gi + (((size_t)(dir * B_ + b)) * S_ + s0) * 192 + j;
    for (int r = 0; r < 64; r++) {
        const float4* xr = (const float4*)xs[r];   // uniform addr -> LDS broadcast
        float a0 = 0.f, a1 = 0.f, a2 = 0.f, a3 = 0.f;
        #pragma unroll
        for (int q = 0; q < E_ / 4; q++) {
            const float4 x = xr[q];
            a0 += x.x * w[4 * q + 0]; a1 += x.y * w[4 * q + 1];
            a2 += x.z * w[4 * q + 2]; a3 += x.w * w[4 * q + 3];
        }
        gout[(size_t)r * 192] = ((a0 + a1) + (a2 + a3)) + c;   // coalesced per r
    }
}

// ---------------------------------------------------------------------------
// K1: encoder BiGRU recurrence. grid = 256 (b, dir), block = 192 = 3 waves.
// Wave g (= tid>>6) owns gate g; lane j holds row g*64+j of Whh as 16 f32x4
// (64 VGPRs -> no spill possible). Per step: each lane computes one 64-long
// dot against hs (LDS broadcast reads), folds gi / biases, writes sg; wave 0
// then applies activations, updates hs[j], stores output. 2 barriers/step.
// gi streamed from global, prefetched 2 steps ahead.
// outputs: bf16 [B][S][H]; sn: fp32 [B][H].
// ---------------------------------------------------------------------------
__global__ __launch_bounds__(192, 1) void encoder_kernel(
    const float* __restrict__ gi,
    const float* __restrict__ Whh_f, const float* __restrict__ bhh_f,
    const float* __restrict__ Whh_b, const float* __restrict__ bhh_b,
    u16* __restrict__ outputs, float* __restrict__ sn)
{
    const int tid = threadIdx.x;
    const int g = tid >> 6;                 // wave / gate 0..2
    const int j = tid & 63;                 // lane
    const int b = blockIdx.x & 127;
    const int dir = blockIdx.x >> 7;

    const float* Whh = dir ? Whh_b : Whh_f;
    const float* bhh = dir ? bhh_b : bhh_f;

    // 64 weights/lane: row (g*64+j) of Whh. 16 f32x4, constant-indexed.
    f32x4 wv[16];
    {
        const f32x4* wr = (const f32x4*)(Whh + (g * 64 + j) * 64);
        #pragma unroll
        for (int k = 0; k < 16; k++) wv[k] = wr[k];
    }
    // gate n: b_hh[128+j] is inside the r*( ) term -> fold into the gh sum
    const float badd = (g == 2) ? bhh[128 + j] : 0.f;

    __shared__ __attribute__((aligned(16))) float hs[64];
    __shared__ float sg[4 * 64];   // [0:64) r-pre, [64:128) z-pre, [128:192) gh_n+bhh, [192:256) gi_n
    if (tid < 64) hs[tid] = 0.f;
    float hmine = 0.f;             // tracked by wave 0

    const float* gp = gi + ((size_t)(dir * B_ + b)) * S_ * 192 + g * 64 + j;
    u16* orow = outputs + ((size_t)b * S_) * H_ + (dir << 6) + j;   // wave 0 only

    const int st = dir ? -1 : 1;
    int oc = dir ? (S_ - 1) : 0;

    // 2-deep gi prefetch. OOB step indices (oc +- 2) stay inside the gi
    // allocation; values are never consumed.
    float pa = gp[(long)oc * 192];
    float pb = gp[(long)(oc + st) * 192];

#define ENC_STEP(PCUR)                                                         \
    {                                                                          \
        __syncthreads();               /* hs ready; prev sg reads retired */   \
        f32x4 acc = {0.f, 0.f, 0.f, 0.f};                                      \
        _Pragma("unroll")                                                      \
        for (int q = 0; q < 16; q++)                                           \
            acc += *(const f32x4*)(hs + 4 * q) * wv[q];                        \
        const float d = (acc[0] + acc[1]) + (acc[2] + acc[3]);                 \
        if (g == 2) { sg[128 + j] = d + badd; sg[192 + j] = PCUR; }            \
        else        { sg[g * 64 + j] = d + PCUR; }                             \
        PCUR = gp[(long)(oc + 2 * st) * 192];   /* prefetch step s+2 */        \
        __syncthreads();               /* sg ready */                          \
        if (g == 0) {                                                          \
            const float r = sigm_fast(sg[j]);                                  \
            const float z = sigm_fast(sg[64 + j]);                             \
            const float n = tanh_fast(sg[192 + j] + r * sg[128 + j]);          \
            const float hn = n + z * (hmine - n);                              \
            hmine = hn;                                                        \
            hs[j] = hn;                                                        \
            orow[(long)oc * H_] = f2bf(hn);                                    \
        }                                                                      \
        oc += st;                                                              \
    }

    for (int s = 0; s < S_; s += 2) {
        ENC_STEP(pa)
        ENC_STEP(pb)
    }
#undef ENC_STEP

    if (g == 0) sn[(b << 7) + (dir << 6) + j] = hmine;
}

// ---------------------------------------------------------------------------
// K2: t2[b][h] = sn[b] . W2[h] + b2[h].  grid=128, block=128. All fp32.
// ---------------------------------------------------------------------------
__global__ __launch_bounds__(128) void t2_kernel(
    const float* __restrict__ sn, const float* __restrict__ W2,
    const float* __restrict__ b2, float* __restrict__ t2)
{
    const int b = blockIdx.x, h = threadIdx.x;
    __shared__ float s_[H_];
    s_[h] = sn[b * H_ + h];
    __syncthreads();
    const float4* wr = (const float4*)(W2 + h * H_);
    float a0 = 0.f, a1 = 0.f, a2 = 0.f, a3 = 0.f;
    #pragma unroll 4
    for (int k = 0; k < H_ / 4; k++) {
        const float4 p = wr[k];
        a0 += s_[4 * k + 0] * p.x; a1 += s_[4 * k + 1] * p.y;
        a2 += s_[4 * k + 2] * p.z; a3 += s_[4 * k + 3] * p.w;
    }
    t2[b * H_ + h] = ((a0 + a1) + (a2 + a3)) + b2[h];
}

// ---------------------------------------------------------------------------
// K3: fp32 -> bf16 conversion (used for W1 and W_out). 4 elems/thread.
// ---------------------------------------------------------------------------
__global__ __launch_bounds__(256) void cvt_bf16_kernel(
    const float* __restrict__ src, u16* __restrict__ dst)
{
    const int i = (blockIdx.x * 256 + threadIdx.x) * 4;
    const float4 p = *(const float4*)(src + i);
    ushort4 q;
    q.x = f2bf(p.x); q.y = f2bf(p.y); q.z = f2bf(p.z); q.w = f2bf(p.w);
    *(ushort4*)(dst + i) = q;
}

// ---------------------------------------------------------------------------
// K4: gate via MFMA. pre[m][n] = outputs[m] . W1[n];
// enc[m][n] = outputs[m][n] * sigmoid(pre + b1[n] + t2[b][n]),  b = m>>9.
// M=65536 rows, N=128, K=128. Block = 4 waves, tile 64(M)x128(N). grid=1024.
// ---------------------------------------------------------------------------
__global__ __launch_bounds__(256) void gate_mfma_kernel(
    const u16* __restrict__ outputs, const u16* __restrict__ W1b,
    const float* __restrict__ b1, const float* __restrict__ t2,
    u16* __restrict__ enc)
{
    const int l = threadIdx.x & 63;
    const int w = threadIdx.x >> 6;
    const int tile_m = blockIdx.x * 64 + w * 16;
    const int row_a = tile_m + (l & 15);
    const int kb = (l >> 4) * 8;
    const int b = blockIdx.x >> 3;           // 8 blocks of 64 rows per batch

    f32x4 acc[8] = {};
    #pragma unroll
    for (int kk = 0; kk < 4; kk++) {
        const int k0 = kk * 32 + kb;
        const short8 af = *(const short8*)(outputs + row_a * H_ + k0);
        #pragma unroll
        for (int i = 0; i < 8; i++) {
            const int n = i * 16 + (l & 15);
            const short8 bv = *(const short8*)(W1b + n * H_ + k0);
            acc[i] = __builtin_amdgcn_mfma_f32_16x16x32_bf16(af, bv, acc[i], 0, 0, 0);
        }
    }

    const int m_base = tile_m + (l >> 4) * 4;
    #pragma unroll
    for (int i = 0; i < 8; i++) {
        const int n = i * 16 + (l & 15);
        const float bias = b1[n] + t2[b * H_ + n];
        #pragma unroll
        for (int r = 0; r < 4; r++) {
            const int m = m_base + r;
            const float g = sigm_fast(acc[i][r] + bias);
            const float o = bfu(outputs[m * H_ + n]);
            enc[m * H_ + n] = f2bf(o * g);
        }
    }
}

// ---------------------------------------------------------------------------
// K5: decoder. grid = 128 (one WG per batch), block = 512 = 8 waves. 15 steps.
// enc slice (512x128 bf16 = 128KB) staged in LDS ONCE with 16B-chunk XOR
// swizzle: chunk c of row s lives at position c^(s&15) within the row.
// pass1: 1 row/thread from LDS. softmax: shuffle + 8-entry combine. pass2:
// thread owns 8-k chunk x 16 s (16 ds_read_b128), 32-partition LDS reduce.
// gates: 1 row/thread (384/512), weights fp32 from L2 (now unthrashed).
// ---------------------------------------------------------------------------
__global__ __launch_bounds__(512, 1) void decoder_kernel(
    const int* __restrict__ targets, const float* __restrict__ emb,
    const float* __restrict__ Wihd, const float* __restrict__ Whhd,
    const float* __restrict__ bihd, const float* __restrict__ bhhd,
    const u16* __restrict__ enc, const float* __restrict__ sn,
    u16* __restrict__ h_all)
{
    const int b = blockIdx.x;
    const int tid = threadIdx.x;
    const int lane = tid & 63;
    const int wid = tid >> 6;                 // 0..7

    __shared__ __attribute__((aligned(16))) u16 enc_lds[S_ * H_];  // 128 KB, swizzled
    __shared__ __attribute__((aligned(16))) float h[H_];
    __shared__ float sc[S_];
    __shared__ float xv[H_ + E_];             // [c(128), e(32)]
    __shared__ float redm[8], reds[8];
    __shared__ __attribute__((aligned(16))) float cpart[32][H_];   // 16 KB
    __shared__ float sgi[3 * H_];
    __shared__ float sgh[3 * H_];

    const u16* encb = enc + b * S_ * H_;

    // ---- stage enc slice into LDS (once), swizzled ----
    // thread handles (s = 32*i + (tid>>4), c = tid&15), i = 0..15.
    // global: 16 lanes read 16 consecutive 16B chunks of one row (coalesced);
    // LDS: pos = c ^ (s&15) -> 16 distinct positions -> uniform bank spread.
    {
        const int c = tid & 15;
        const int sb = tid >> 4;              // 0..31
        #pragma unroll
        for (int i = 0; i < 16; i++) {
            const int s = i * 32 + sb;
            const uint4 p = *(const uint4*)(encb + s * H_ + c * 8);
            *(uint4*)(enc_lds + s * H_ + ((c ^ (s & 15)) * 8)) = p;
        }
    }
    if (tid < H_) h[tid] = sn[b * H_ + tid];
    __syncthreads();

    for (int t = 0; t < TDEC; t++) {
        const int word = targets[b * 16 + t];

        // ---- pass 1: score d = h . enc[s=tid], from swizzled LDS ----
        float d;
        {
            const int s = tid;
            const int sx = s & 15;
            float a0 = 0.f, a1 = 0.f, a2 = 0.f, a3 = 0.f;
            #pragma unroll
            for (int c = 0; c < 16; c++) {
                const uint4 p = *(const uint4*)(enc_lds + s * H_ + ((c ^ sx) * 8));
                float f[8]; bf8_to_f(p, f);
                const f32x4 h0 = *(const f32x4*)(h + c * 8);
                const f32x4 h1 = *(const f32x4*)(h + c * 8 + 4);
                a0 += h0[0] * f[0]; a1 += h0[1] * f[1];
                a2 += h0[2] * f[2]; a3 += h0[3] * f[3];
                a0 += h1[0] * f[4]; a1 += h1[1] * f[5];
                a2 += h1[2] * f[6]; a3 += h1[3] * f[7];
            }
            d = (a0 + a1) + (a2 + a3);
        }

        // ---- softmax over 512: wave shuffle reduce + cross-wave combine ----
        float m = d;
        #pragma unroll
        for (int off = 32; off > 0; off >>= 1) m = fmaxf(m, __shfl_xor(m, off));
        if (lane == 0) redm[wid] = m;
        __syncthreads();                                   // B1
        float bm = redm[0];
        #pragma unroll
        for (int i = 1; i < 8; i++) bm = fmaxf(bm, redm[i]);
        const float e = expf(d - bm);
        float ssum = e;
        #pragma unroll
        for (int off = 32; off > 0; off >>= 1) ssum += __shfl_xor(ssum, off);
        if (lane == 0) reds[wid] = ssum;
        __syncthreads();                                   // B2
        float tot = reds[0];
        #pragma unroll
        for (int i = 1; i < 8; i++) tot += reds[i];
        sc[tid] = e * (1.f / tot);
        __syncthreads();                                   // B3

        // ---- pass 2: c[k] = sum_s alpha[s] enc[s][k]; thread owns 8-k chunk
        //      (c = tid&15) x 16 s (q = tid>>4), from swizzled LDS ----
        {
            const int c = tid & 15;
            const int q = tid >> 4;                        // 0..31
            f32x4 ca = {0.f, 0.f, 0.f, 0.f}, cb = {0.f, 0.f, 0.f, 0.f};
            #pragma unroll
            for (int i = 0; i < 16; i++) {
                const int s = q * 16 + i;
                const float al = sc[s];
                const uint4 p = *(const uint4*)(enc_lds + s * H_ + ((c ^ i) * 8));
                float f[8]; bf8_to_f(p, f);
                ca[0] += al * f[0]; ca[1] += al * f[1];
                ca[2] += al * f[2]; ca[3] += al * f[3];
                cb[0] += al * f[4]; cb[1] += al * f[5];
                cb[2] += al * f[6]; cb[3] += al * f[7];
            }
            *(f32x4*)(cpart[q] + c * 8) = ca;
            *(f32x4*)(cpart[q] + c * 8 + 4) = cb;
        }
        __syncthreads();                                   // B4
        if (tid < H_) {
            float s0 = 0.f, s1 = 0.f, s2 = 0.f, s3 = 0.f;
            #pragma unroll
            for (int p = 0; p < 32; p += 4) {
                s0 += cpart[p + 0][tid]; s1 += cpart[p + 1][tid];
                s2 += cpart[p + 2][tid]; s3 += cpart[p + 3][tid];
            }
            xv[tid] = (s0 + s1) + (s2 + s3);
        } else if (tid < H_ + E_) xv[tid] = emb[(unsigned)word * E_ + (tid - H_)];
        __syncthreads();                                   // B5

        // ---- gates: one row per thread (tid < 384), fp32 weights from L2 ----
        if (tid < 3 * H_) {
            const int j = tid;
            const float4* wr = (const float4*)(Wihd + j * (H_ + E_));
            float g0 = 0.f, g1 = 0.f, g2 = 0.f, g3 = 0.f;
            #pragma unroll 8
            for (int k = 0; k < (H_ + E_) / 4; k++) {
                const float4 p = wr[k];
                g0 += xv[4 * k + 0] * p.x; g1 += xv[4 * k + 1] * p.y;
                g2 += xv[4 * k + 2] * p.z; g3 += xv[4 * k + 3] * p.w;
            }
            sgi[j] = ((g0 + g1) + (g2 + g3)) + bihd[j];

            const float4* hr = (const float4*)(Whhd + j * H_);
            float b0 = 0.f, b1_ = 0.f, b2_ = 0.f, b3 = 0.f;
            #pragma unroll 8
            for (int k = 0; k < H_ / 4; k++) {
                const float4 p = hr[k];
                b0  += h[4 * k + 0] * p.x; b1_ += h[4 * k + 1] * p.y;
                b2_ += h[4 * k + 2] * p.z; b3  += h[4 * k + 3] * p.w;
            }
            sgh[j] = ((b0 + b1_) + (b2_ + b3)) + bhhd[j];
        }
        __syncthreads();                                   // B6

        if (tid < H_) {
            const float r = sigm(sgi[tid] + sgh[tid]);
            const float z = sigm(sgi[H_ + tid] + sgh[H_ + tid]);
            const float n = tanhf(sgi[2 * H_ + tid] + r * sgh[2 * H_ + tid]);
            const float hn = (1.f - z) * n + z * h[tid];
            h[tid] = hn;
            h_all[(t * B_ + b) * H_ + tid] = f2bf(hn);
        }
        __syncthreads();                                   // B7
    }
}

// ---------------------------------------------------------------------------
// K6: logits = h_all @ Woutb^T + b_out. MFMA bf16 NT GEMM, fp32 out.
// M=1920 (t*128+b), N=32000, K=128. grid=(500,30), block=256.
// Output: out[(b*15 + t)*32000 + n], fp32.
// ---------------------------------------------------------------------------
__global__ __launch_bounds__(256) void logits_kernel(
    const u16* __restrict__ hall, const u16* __restrict__ Woutb,
    const float* __restrict__ bout, float* __restrict__ out)
{
    const int l = threadIdx.x & 63;
    const int w = threadIdx.x >> 6;
    const int tile_n = blockIdx.x * 64;
    const int tile_m = blockIdx.y * 64 + w * 16;

    f32x4 acc[4] = {};
    const int row_a = tile_m + (l & 15);
    const int kb = (l >> 4) * 8;

    #pragma unroll
    for (int kk = 0; kk < 4; kk++) {
        const int k0 = kk * 32 + kb;
        const short8 af = *(const short8*)(hall + row_a * H_ + k0);
        #pragma unroll
        for (int i = 0; i < 4; i++) {
            const int n = tile_n + i * 16 + (l & 15);
            const short8 bv = *(const short8*)(Woutb + n * H_ + k0);
            acc[i] = __builtin_amdgcn_mfma_f32_16x16x32_bf16(af, bv, acc[i], 0, 0, 0);
        }
    }

    const int m_base = tile_m + (l >> 4) * 4;
    #pragma unroll
    for (int i = 0; i < 4; i++) {
        const int n = tile_n + i * 16 + (l & 15);
        const float bias = bout[n];
        #pragma unroll
        for (int r = 0; r < 4; r++) {
            const int m = m_base + r;
            const int t = m >> 7;
            const int bb = m & 127;
            out[(size_t)(bb * TDEC + t) * V_ + n] = acc[i][r] + bias;
        }
    }
}

// ---------------------------------------------------------------------------
extern "C" void kernel_launch(void* const* d_in, const int* in_sizes, int n_in,
                              void* d_out, int out_size, void* d_ws, size_t ws_size,
                              hipStream_t stream) {
    const int*   inputs  = (const int*)d_in[0];
    const int*   targets = (const int*)d_in[1];
    const float* emb     = (const float*)d_in[2];
    const float* Wih_f   = (const float*)d_in[3];
    const float* Whh_f   = (const float*)d_in[4];
    const float* bih_f   = (const float*)d_in[5];
    const float* bhh_f   = (const float*)d_in[6];
    const float* Wih_b   = (const float*)d_in[7];
    const float* Whh_b   = (const float*)d_in[8];
    const float* bih_b   = (const float*)d_in[9];
    const float* bhh_b   = (const float*)d_in[10];
    const float* W1      = (const float*)d_in[11];
    const float* b1      = (const float*)d_in[12];
    const float* W2      = (const float*)d_in[13];
    const float* b2      = (const float*)d_in[14];
    const float* Wihd    = (const float*)d_in[15];
    const float* Whhd    = (const float*)d_in[16];
    const float* bihd    = (const float*)d_in[17];
    const float* bhhd    = (const float*)d_in[18];
    const float* Wout    = (const float*)d_in[19];
    const float* bout    = (const float*)d_in[20];
    float* out = (float*)d_out;

    // Staging at the front of d_out (245.76 MB). The logits kernel runs last
    // and overwrites every element of d_out with the real output.
    u16*   outputs = (u16*)d_out;                       // bf16 B*S*H = 16,777,216 B
    u16*   enc     = (u16*)((char*)d_out + 16777216);   // bf16 B*S*H = 16,777,216 B
    u16*   W1b     = (u16*)((char*)d_out + 33554432);   // bf16 H*H   =     32,768 B
    float* gi      = (float*)((char*)d_out + 33619968); // f32 2*B*S*192 = 100,663,296 B (ends @134MB < 245MB)

    // d_ws: small state only (8.82 MB total) — layout validated in R3.
    char* ws = (char*)d_ws;
    float* sn    = (float*)(ws);                 // B*H  f32    =  65,536 B
    float* t2    = (float*)(ws + 65536);         // B*H  f32    =  65,536 B
    u16*   h_all = (u16*)(ws + 131072);          // 15*B*H bf16 = 491,520 B
    u16*   Woutb = (u16*)(ws + 622592);          // V*H bf16    = 8,192,000 B

    gi_kernel<<<B_ * (S_ / 64), 384, 0, stream>>>(inputs, emb, Wih_f, bih_f, bhh_f,
                                                  Wih_b, bih_b, bhh_b, gi);
    encoder_kernel<<<256, 192, 0, stream>>>(gi, Whh_f, bhh_f, Whh_b, bhh_b, outputs, sn);
    t2_kernel<<<128, 128, 0, stream>>>(sn, W2, b2, t2);
    cvt_bf16_kernel<<<H_ * H_ / 1024, 256, 0, stream>>>(W1, W1b);
    cvt_bf16_kernel<<<V_ * H_ / 1024, 256, 0, stream>>>(Wout, Woutb);
    gate_mfma_kernel<<<B_ * S_ / 64, 256, 0, stream>>>(outputs, W1b, b1, t2, enc);
    decoder_kernel<<<128, 512, 0, stream>>>(targets, emb, Wihd, Whhd, bihd, bhhd,
                                            enc, sn, h_all);
    logits_kernel<<<dim3(500, 30), 256, 0, stream>>>(h_all, Woutb, bout, out);
}

// Round 8
// 945.351 us; speedup vs baseline: 1.9663x; 1.0043x over previous
//
#include <hip/hip_runtime.h>
#include <hip/hip_bf16.h>

// Model: BiGRU encoder (B=128, S=512, E=32, Hh=64) + gated enc_outs +
// 15-step attention GRU decoder (H=128) + logits GEMM (1920x32000x128).
// fp32 inputs/outputs; bf16 internal staging (outputs, enc, h_all, W1b, Woutb).
//
// R12: R11 killed the decoder's L2 thrash (FETCH 96->10MB) but dur only
//      268->255us: LDS-issue + latency bound. Biggest term: gates read
//      xv/h as 288 scalar ds_read_b32 per thread (1728 LDS instr/step).
//      Changes (decoder only):
//      (a) unified xh[288]=[c|e|h] vector, ALL gate + pass1 reads via b128;
//      (b) gate tasks over all 512 threads: 256 fused r/z rows (dot_ih +
//          dot_hh + both biases in one pass), 128 gi_n, 128 gh_n rows;
//      (c) fast-math activations/softmax (__expf) as encoder already uses.

typedef unsigned short u16;
typedef unsigned int u32;
typedef __attribute__((ext_vector_type(8))) short short8;
typedef __attribute__((ext_vector_type(4))) float f32x4;

#define V_ 32000
#define E_ 32
#define H_ 128
#define B_ 128
#define S_ 512
#define TDEC 15   // T-1

__device__ __forceinline__ float bfu(u32 u) {
    union { u32 i; float f; } v; v.i = u << 16; return v.f;
}
__device__ __forceinline__ u16 f2bf(float f) {
    union { float f; u32 i; } v; v.f = f;
    u32 x = v.i;
    u32 r = (x + 0x7fffu + ((x >> 16) & 1u)) >> 16;
    return (u16)r;
}
__device__ __forceinline__ void bf8_to_f(const uint4 p, float* f) {
    f[0] = bfu(p.x & 0xffffu); f[1] = bfu(p.x >> 16);
    f[2] = bfu(p.y & 0xffffu); f[3] = bfu(p.y >> 16);
    f[4] = bfu(p.z & 0xffffu); f[5] = bfu(p.z >> 16);
    f[6] = bfu(p.w & 0xffffu); f[7] = bfu(p.w >> 16);
}
__device__ __forceinline__ float sigm_fast(float x) { return 1.f / (1.f + __expf(-x)); }
__device__ __forceinline__ float tanh_fast(float x) {
    const float t = __expf(2.f * x);          // args bounded ~|x|<15 here: no overflow
    return (t - 1.f) / (t + 1.f);
}

// ---------------------------------------------------------------------------
// K0: gi[dir][b][s][192] = embeds[b][s] . Wih_dir^T + bih (+ bhh for gates r,z).
// No sequential dependence -> fully parallel. grid = 1024 (b, s-chunk of 64),
// block = 384 (one thread per output column: 2 dirs x 192).
// ---------------------------------------------------------------------------
__global__ __launch_bounds__(384) void gi_kernel(
    const int* __restrict__ inputs, const float* __restrict__ emb,
    const float* __restrict__ Wih_f, const float* __restrict__ bih_f,
    const float* __restrict__ bhh_f,
    const float* __restrict__ Wih_b, const float* __restrict__ bih_b,
    const float* __restrict__ bhh_b,
    float* __restrict__ gi)
{
    const int b  = blockIdx.x >> 3;
    const int s0 = (blockIdx.x & 7) << 6;
    const int tid = threadIdx.x;

    __shared__ float xs[64][E_];   // 8 KB
    __shared__ int idx[64];
    if (tid < 64) idx[tid] = inputs[b * S_ + s0 + tid];
    __syncthreads();
    for (int i = tid; i < 64 * E_; i += 384) {
        xs[i >> 5][i & 31] = emb[(unsigned)idx[i >> 5] * E_ + (i & 31)];
    }
    __syncthreads();

    const int dir = (tid >= 192) ? 1 : 0;
    const int j = tid - dir * 192;               // 0..191: gate*64 + elem
    const float* Wih = dir ? Wih_b : Wih_f;
    const float* bih = dir ? bih_b : bih_f;
    const float* bhh = dir ? bhh_b : bhh_f;

    float w[E_];
    #pragma unroll
    for (int k = 0; k < E_; k += 4)
        *(float4*)(w + k) = *(const float4*)(Wih + j * E_ + k);
    // fold both biases for r,z (j<128); only b_ih for n (b_hh[n] stays inside r*(...))
    const float c = bih[j] + (j < 128 ? bhh[j] : 0.f);

    float* gout = gi + (((size_t)(dir * B_ + b)) * S_ + s0) * 192 + j;
    for (int r = 0; r < 64; r++) {
        const float4* xr = (const float4*)xs[r];   // uniform addr -> LDS broadcast
        float a0 = 0.f, a1 = 0.f, a2 = 0.f, a3 = 0.f;
        #pragma unroll
        for (int q = 0; q < E_ / 4; q++) {
            const float4 x = xr[q];
            a0 += x.x * w[4 * q + 0]; a1 += x.y * w[4 * q + 1];
            a2 += x.z * w[4 * q + 2]; a3 += x.w * w[4 * q + 3];
        }
        gout[(size_t)r * 192] = ((a0 + a1) + (a2 + a3)) + c;   // coalesced per r
    }
}

// ---------------------------------------------------------------------------
// K1: encoder BiGRU recurrence. grid = 256 (b, dir), block = 192 = 3 waves.
// Wave g (= tid>>6) owns gate g; lane j holds row g*64+j of Whh as 16 f32x4
// (64 VGPRs -> no spill possible). Per step: each lane computes one 64-long
// dot against hs (LDS broadcast reads), folds gi / biases, writes sg; wave 0
// then applies activations, updates hs[j], stores output. 2 barriers/step.
// gi streamed from global, prefetched 2 steps ahead.
// outputs: bf16 [B][S][H]; sn: fp32 [B][H].
// ---------------------------------------------------------------------------
__global__ __launch_bounds__(192, 1) void encoder_kernel(
    const float* __restrict__ gi,
    const float* __restrict__ Whh_f, const float* __restrict__ bhh_f,
    const float* __restrict__ Whh_b, const float* __restrict__ bhh_b,
    u16* __restrict__ outputs, float* __restrict__ sn)
{
    const int tid = threadIdx.x;
    const int g = tid >> 6;                 // wave / gate 0..2
    const int j = tid & 63;                 // lane
    const int b = blockIdx.x & 127;
    const int dir = blockIdx.x >> 7;

    const float* Whh = dir ? Whh_b : Whh_f;
    const float* bhh = dir ? bhh_b : bhh_f;

    // 64 weights/lane: row (g*64+j) of Whh. 16 f32x4, constant-indexed.
    f32x4 wv[16];
    {
        const f32x4* wr = (const f32x4*)(Whh + (g * 64 + j) * 64);
        #pragma unroll
        for (int k = 0; k < 16; k++) wv[k] = wr[k];
    }
    // gate n: b_hh[128+j] is inside the r*( ) term -> fold into the gh sum
    const float badd = (g == 2) ? bhh[128 + j] : 0.f;

    __shared__ __attribute__((aligned(16))) float hs[64];
    __shared__ float sg[4 * 64];   // [0:64) r-pre, [64:128) z-pre, [128:192) gh_n+bhh, [192:256) gi_n
    if (tid < 64) hs[tid] = 0.f;
    float hmine = 0.f;             // tracked by wave 0

    const float* gp = gi + ((size_t)(dir * B_ + b)) * S_ * 192 + g * 64 + j;
    u16* orow = outputs + ((size_t)b * S_) * H_ + (dir << 6) + j;   // wave 0 only

    const int st = dir ? -1 : 1;
    int oc = dir ? (S_ - 1) : 0;

    // 2-deep gi prefetch. OOB step indices (oc +- 2) stay inside the gi
    // allocation; values are never consumed.
    float pa = gp[(long)oc * 192];
    float pb = gp[(long)(oc + st) * 192];

#define ENC_STEP(PCUR)                                                         \
    {                                                                          \
        __syncthreads();               /* hs ready; prev sg reads retired */   \
        f32x4 acc = {0.f, 0.f, 0.f, 0.f};                                      \
        _Pragma("unroll")                                                      \
        for (int q = 0; q < 16; q++)                                           \
            acc += *(const f32x4*)(hs + 4 * q) * wv[q];                        \
        const float d = (acc[0] + acc[1]) + (acc[2] + acc[3]);                 \
        if (g == 2) { sg[128 + j] = d + badd; sg[192 + j] = PCUR; }            \
        else        { sg[g * 64 + j] = d + PCUR; }                             \
        PCUR = gp[(long)(oc + 2 * st) * 192];   /* prefetch step s+2 */        \
        __syncthreads();               /* sg ready */                          \
        if (g == 0) {                                                          \
            const float r = sigm_fast(sg[j]);                                  \
            const float z = sigm_fast(sg[64 + j]);                             \
            const float n = tanh_fast(sg[192 + j] + r * sg[128 + j]);          \
            const float hn = n + z * (hmine - n);                              \
            hmine = hn;                                                        \
            hs[j] = hn;                                                        \
            orow[(long)oc * H_] = f2bf(hn);                                    \
        }                                                                      \
        oc += st;                                                              \
    }

    for (int s = 0; s < S_; s += 2) {
        ENC_STEP(pa)
        ENC_STEP(pb)
    }
#undef ENC_STEP

    if (g == 0) sn[(b << 7) + (dir << 6) + j] = hmine;
}

// ---------------------------------------------------------------------------
// K2: t2[b][h] = sn[b] . W2[h] + b2[h].  grid=128, block=128. All fp32.
// ---------------------------------------------------------------------------
__global__ __launch_bounds__(128) void t2_kernel(
    const float* __restrict__ sn, const float* __restrict__ W2,
    const float* __restrict__ b2, float* __restrict__ t2)
{
    const int b = blockIdx.x, h = threadIdx.x;
    __shared__ float s_[H_];
    s_[h] = sn[b * H_ + h];
    __syncthreads();
    const float4* wr = (const float4*)(W2 + h * H_);
    float a0 = 0.f, a1 = 0.f, a2 = 0.f, a3 = 0.f;
    #pragma unroll 4
    for (int k = 0; k < H_ / 4; k++) {
        const float4 p = wr[k];
        a0 += s_[4 * k + 0] * p.x; a1 += s_[4 * k + 1] * p.y;
        a2 += s_[4 * k + 2] * p.z; a3 += s_[4 * k + 3] * p.w;
    }
    t2[b * H_ + h] = ((a0 + a1) + (a2 + a3)) + b2[h];
}

// ---------------------------------------------------------------------------
// K3: fp32 -> bf16 conversion (used for W1 and W_out). 4 elems/thread.
// ---------------------------------------------------------------------------
__global__ __launch_bounds__(256) void cvt_bf16_kernel(
    const float* __restrict__ src, u16* __restrict__ dst)
{
    const int i = (blockIdx.x * 256 + threadIdx.x) * 4;
    const float4 p = *(const float4*)(src + i);
    ushort4 q;
    q.x = f2bf(p.x); q.y = f2bf(p.y); q.z = f2bf(p.z); q.w = f2bf(p.w);
    *(ushort4*)(dst + i) = q;
}

// ---------------------------------------------------------------------------
// K4: gate via MFMA. pre[m][n] = outputs[m] . W1[n];
// enc[m][n] = outputs[m][n] * sigmoid(pre + b1[n] + t2[b][n]),  b = m>>9.
// M=65536 rows, N=128, K=128. Block = 4 waves, tile 64(M)x128(N). grid=1024.
// ---------------------------------------------------------------------------
__global__ __launch_bounds__(256) void gate_mfma_kernel(
    const u16* __restrict__ outputs, const u16* __restrict__ W1b,
    const float* __restrict__ b1, const float* __restrict__ t2,
    u16* __restrict__ enc)
{
    const int l = threadIdx.x & 63;
    const int w = threadIdx.x >> 6;
    const int tile_m = blockIdx.x * 64 + w * 16;
    const int row_a = tile_m + (l & 15);
    const int kb = (l >> 4) * 8;
    const int b = blockIdx.x >> 3;           // 8 blocks of 64 rows per batch

    f32x4 acc[8] = {};
    #pragma unroll
    for (int kk = 0; kk < 4; kk++) {
        const int k0 = kk * 32 + kb;
        const short8 af = *(const short8*)(outputs + row_a * H_ + k0);
        #pragma unroll
        for (int i = 0; i < 8; i++) {
            const int n = i * 16 + (l & 15);
            const short8 bv = *(const short8*)(W1b + n * H_ + k0);
            acc[i] = __builtin_amdgcn_mfma_f32_16x16x32_bf16(af, bv, acc[i], 0, 0, 0);
        }
    }

    const int m_base = tile_m + (l >> 4) * 4;
    #pragma unroll
    for (int i = 0; i < 8; i++) {
        const int n = i * 16 + (l & 15);
        const float bias = b1[n] + t2[b * H_ + n];
        #pragma unroll
        for (int r = 0; r < 4; r++) {
            const int m = m_base + r;
            const float g = sigm_fast(acc[i][r] + bias);
            const float o = bfu(outputs[m * H_ + n]);
            enc[m * H_ + n] = f2bf(o * g);
        }
    }
}

// ---------------------------------------------------------------------------
// K5: decoder. grid = 128 (one WG per batch), block = 512 = 8 waves. 15 steps.
// enc slice (512x128 bf16 = 128KB) staged in LDS ONCE with 16B-chunk XOR
// swizzle (pos = c^(s&15)). Unified xh[288] = [c_t(128) | emb(32) | h(128)];
// all pass1/gate vector reads are b128 broadcasts.
// Gate tasks over all 512 threads: tid<256 fused r/z row (dot_ih+dot_hh+both
// biases), tid<384 gi_n row, else gh_n row. Fast-math activations.
// ---------------------------------------------------------------------------
__global__ __launch_bounds__(512, 1) void decoder_kernel(
    const int* __restrict__ targets, const float* __restrict__ emb,
    const float* __restrict__ Wihd, const float* __restrict__ Whhd,
    const float* __restrict__ bihd, const float* __restrict__ bhhd,
    const u16* __restrict__ enc, const float* __restrict__ sn,
    u16* __restrict__ h_all)
{
    const int b = blockIdx.x;
    const int tid = threadIdx.x;
    const int lane = tid & 63;
    const int wid = tid >> 6;                 // 0..7

    __shared__ __attribute__((aligned(16))) u16 enc_lds[S_ * H_];  // 128 KB, swizzled
    __shared__ __attribute__((aligned(16))) float xh[288];         // [c|e|h]
    __shared__ float sc[S_];
    __shared__ float redm[8], reds[8];
    __shared__ __attribute__((aligned(16))) float cpart[32][H_];   // 16 KB
    __shared__ float gf[256];                 // fused r(0..127)/z(128..255) pre-act
    __shared__ float gin[128], ghn[128];      // n-gate: gi_n, gh_n (+biases)

    const u16* encb = enc + b * S_ * H_;

    // ---- stage enc slice into LDS (once), swizzled ----
    {
        const int c = tid & 15;
        const int sb = tid >> 4;              // 0..31
        #pragma unroll
        for (int i = 0; i < 16; i++) {
            const int s = i * 32 + sb;
            const uint4 p = *(const uint4*)(encb + s * H_ + c * 8);
            *(uint4*)(enc_lds + s * H_ + ((c ^ (s & 15)) * 8)) = p;
        }
    }
    if (tid < H_) xh[160 + tid] = sn[b * H_ + tid];
    __syncthreads();

    for (int t = 0; t < TDEC; t++) {
        const int word = targets[b * 16 + t];

        // ---- pass 1: score d = h . enc[s=tid], from swizzled LDS ----
        float d;
        {
            const int s = tid;
            const int sx = s & 15;
            float a0 = 0.f, a1 = 0.f, a2 = 0.f, a3 = 0.f;
            #pragma unroll
            for (int c = 0; c < 16; c++) {
                const uint4 p = *(const uint4*)(enc_lds + s * H_ + ((c ^ sx) * 8));
                float f[8]; bf8_to_f(p, f);
                const f32x4 h0 = *(const f32x4*)(xh + 160 + c * 8);
                const f32x4 h1 = *(const f32x4*)(xh + 160 + c * 8 + 4);
                a0 += h0[0] * f[0]; a1 += h0[1] * f[1];
                a2 += h0[2] * f[2]; a3 += h0[3] * f[3];
                a0 += h1[0] * f[4]; a1 += h1[1] * f[5];
                a2 += h1[2] * f[6]; a3 += h1[3] * f[7];
            }
            d = (a0 + a1) + (a2 + a3);
        }

        // ---- softmax over 512: wave shuffle reduce + cross-wave combine ----
        float m = d;
        #pragma unroll
        for (int off = 32; off > 0; off >>= 1) m = fmaxf(m, __shfl_xor(m, off));
        if (lane == 0) redm[wid] = m;
        __syncthreads();                                   // B1
        float bm = redm[0];
        #pragma unroll
        for (int i = 1; i < 8; i++) bm = fmaxf(bm, redm[i]);
        const float e = __expf(d - bm);
        float ssum = e;
        #pragma unroll
        for (int off = 32; off > 0; off >>= 1) ssum += __shfl_xor(ssum, off);
        if (lane == 0) reds[wid] = ssum;
        __syncthreads();                                   // B2
        float tot = reds[0];
        #pragma unroll
        for (int i = 1; i < 8; i++) tot += reds[i];
        sc[tid] = e * (1.f / tot);
        __syncthreads();                                   // B3

        // ---- pass 2: c[k] = sum_s alpha[s] enc[s][k]; thread owns 8-k chunk
        //      (c = tid&15) x 16 s (q = tid>>4), from swizzled LDS ----
        {
            const int c = tid & 15;
            const int q = tid >> 4;                        // 0..31
            f32x4 ca = {0.f, 0.f, 0.f, 0.f}, cb = {0.f, 0.f, 0.f, 0.f};
            #pragma unroll
            for (int i = 0; i < 16; i++) {
                const int s = q * 16 + i;
                const float al = sc[s];
                const uint4 p = *(const uint4*)(enc_lds + s * H_ + ((c ^ i) * 8));
                float f[8]; bf8_to_f(p, f);
                ca[0] += al * f[0]; ca[1] += al * f[1];
                ca[2] += al * f[2]; ca[3] += al * f[3];
                cb[0] += al * f[4]; cb[1] += al * f[5];
                cb[2] += al * f[6]; cb[3] += al * f[7];
            }
            *(f32x4*)(cpart[q] + c * 8) = ca;
            *(f32x4*)(cpart[q] + c * 8 + 4) = cb;
        }
        __syncthreads();                                   // B4
        if (tid < H_) {
            float s0 = 0.f, s1 = 0.f, s2 = 0.f, s3 = 0.f;
            #pragma unroll
            for (int p = 0; p < 32; p += 4) {
                s0 += cpart[p + 0][tid]; s1 += cpart[p + 1][tid];
                s2 += cpart[p + 2][tid]; s3 += cpart[p + 3][tid];
            }
            xh[tid] = (s0 + s1) + (s2 + s3);
        } else if (tid < H_ + E_) xh[tid] = emb[(unsigned)word * E_ + (tid - H_)];
        __syncthreads();                                   // B5

        // ---- gates: 512 task split; all xh reads are b128 broadcasts ----
        if (tid < 256) {
            // fused r/z row j: sigm arg = dot_ih + dot_hh + bih + bhh
            const int j = tid;
            const float4* wr = (const float4*)(Wihd + j * (H_ + E_));
            const float4* xr = (const float4*)(xh);
            float g0 = 0.f, g1 = 0.f, g2 = 0.f, g3 = 0.f;
            #pragma unroll 8
            for (int k = 0; k < (H_ + E_) / 4; k++) {
                const float4 p = wr[k];
                const float4 x = xr[k];
                g0 += x.x * p.x; g1 += x.y * p.y; g2 += x.z * p.z; g3 += x.w * p.w;
            }
            const float4* hr = (const float4*)(Whhd + j * H_);
            const float4* xr2 = (const float4*)(xh + 160);
            #pragma unroll 8
            for (int k = 0; k < H_ / 4; k++) {
                const float4 p = hr[k];
                const float4 x = xr2[k];
                g0 += x.x * p.x; g1 += x.y * p.y; g2 += x.z * p.z; g3 += x.w * p.w;
            }
            gf[j] = ((g0 + g1) + (g2 + g3)) + (bihd[j] + bhhd[j]);
        } else if (tid < 384) {
            // gi_n row j = tid (256..383)
            const int j = tid;
            const float4* wr = (const float4*)(Wihd + j * (H_ + E_));
            const float4* xr = (const float4*)(xh);
            float g0 = 0.f, g1 = 0.f, g2 = 0.f, g3 = 0.f;
            #pragma unroll 8
            for (int k = 0; k < (H_ + E_) / 4; k++) {
                const float4 p = wr[k];
                const float4 x = xr[k];
                g0 += x.x * p.x; g1 += x.y * p.y; g2 += x.z * p.z; g3 += x.w * p.w;
            }
            gin[j - 256] = ((g0 + g1) + (g2 + g3)) + bihd[j];
        } else {
            // gh_n row j = tid-128 (256..383)
            const int j = tid - 128;
            const float4* hr = (const float4*)(Whhd + j * H_);
            const float4* xr2 = (const float4*)(xh + 160);
            float g0 = 0.f, g1 = 0.f, g2 = 0.f, g3 = 0.f;
            #pragma unroll 8
            for (int k = 0; k < H_ / 4; k++) {
                const float4 p = hr[k];
                const float4 x = xr2[k];
                g0 += x.x * p.x; g1 += x.y * p.y; g2 += x.z * p.z; g3 += x.w * p.w;
            }
            ghn[j - 256] = ((g0 + g1) + (g2 + g3)) + bhhd[j];
        }
        __syncthreads();                                   // B6

        if (tid < H_) {
            const float r = sigm_fast(gf[tid]);
            const float z = sigm_fast(gf[128 + tid]);
            const float n = tanh_fast(gin[tid] + r * ghn[tid]);
            const float hn = (1.f - z) * n + z * xh[160 + tid];
            xh[160 + tid] = hn;
            h_all[(t * B_ + b) * H_ + tid] = f2bf(hn);
        }
        __syncthreads();                                   // B7
    }
}

// ---------------------------------------------------------------------------
// K6: logits = h_all @ Woutb^T + b_out. MFMA bf16 NT GEMM, fp32 out.
// M=1920 (t*128+b), N=32000, K=128. grid=(500,30), block=256.
// Output: out[(b*15 + t)*32000 + n], fp32.
// ---------------------------------------------------------------------------
__global__ __launch_bounds__(256) void logits_kernel(
    const u16* __restrict__ hall, const u16* __restrict__ Woutb,
    const float* __restrict__ bout, float* __restrict__ out)
{
    const int l = threadIdx.x & 63;
    const int w = threadIdx.x >> 6;
    const int tile_n = blockIdx.x * 64;
    const int tile_m = blockIdx.y * 64 + w * 16;

    f32x4 acc[4] = {};
    const int row_a = tile_m + (l & 15);
    const int kb = (l >> 4) * 8;

    #pragma unroll
    for (int kk = 0; kk < 4; kk++) {
        const int k0 = kk * 32 + kb;
        const short8 af = *(const short8*)(hall + row_a * H_ + k0);
        #pragma unroll
        for (int i = 0; i < 4; i++) {
            const int n = tile_n + i * 16 + (l & 15);
            const short8 bv = *(const short8*)(Woutb + n * H_ + k0);
            acc[i] = __builtin_amdgcn_mfma_f32_16x16x32_bf16(af, bv, acc[i], 0, 0, 0);
        }
    }

    const int m_base = tile_m + (l >> 4) * 4;
    #pragma unroll
    for (int i = 0; i < 4; i++) {
        const int n = tile_n + i * 16 + (l & 15);
        const float bias = bout[n];
        #pragma unroll
        for (int r = 0; r < 4; r++) {
            const int m = m_base + r;
            const int t = m >> 7;
            const int bb = m & 127;
            out[(size_t)(bb * TDEC + t) * V_ + n] = acc[i][r] + bias;
        }
    }
}

// ---------------------------------------------------------------------------
extern "C" void kernel_launch(void* const* d_in, const int* in_sizes, int n_in,
                              void* d_out, int out_size, void* d_ws, size_t ws_size,
                              hipStream_t stream) {
    const int*   inputs  = (const int*)d_in[0];
    const int*   targets = (const int*)d_in[1];
    const float* emb     = (const float*)d_in[2];
    const float* Wih_f   = (const float*)d_in[3];
    const float* Whh_f   = (const float*)d_in[4];
    const float* bih_f   = (const float*)d_in[5];
    const float* bhh_f   = (const float*)d_in[6];
    const float* Wih_b   = (const float*)d_in[7];
    const float* Whh_b   = (const float*)d_in[8];
    const float* bih_b   = (const float*)d_in[9];
    const float* bhh_b   = (const float*)d_in[10];
    const float* W1      = (const float*)d_in[11];
    const float* b1      = (const float*)d_in[12];
    const float* W2      = (const float*)d_in[13];
    const float* b2      = (const float*)d_in[14];
    const float* Wihd    = (const float*)d_in[15];
    const float* Whhd    = (const float*)d_in[16];
    const float* bihd    = (const float*)d_in[17];
    const float* bhhd    = (const float*)d_in[18];
    const float* Wout    = (const float*)d_in[19];
    const float* bout    = (const float*)d_in[20];
    float* out = (float*)d_out;

    // Staging at the front of d_out (245.76 MB). The logits kernel runs last
    // and overwrites every element of d_out with the real output.
    u16*   outputs = (u16*)d_out;                       // bf16 B*S*H = 16,777,216 B
    u16*   enc     = (u16*)((char*)d_out + 16777216);   // bf16 B*S*H = 16,777,216 B
    u16*   W1b     = (u16*)((char*)d_out + 33554432);   // bf16 H*H   =     32,768 B
    float* gi      = (float*)((char*)d_out + 33619968); // f32 2*B*S*192 = 100,663,296 B (ends @134MB < 245MB)

    // d_ws: small state only (8.82 MB total) — layout validated in R3.
    char* ws = (char*)d_ws;
    float* sn    = (float*)(ws);                 // B*H  f32    =  65,536 B
    float* t2    = (float*)(ws + 65536);         // B*H  f32    =  65,536 B
    u16*   h_all = (u16*)(ws + 131072);          // 15*B*H bf16 = 491,520 B
    u16*   Woutb = (u16*)(ws + 622592);          // V*H bf16    = 8,192,000 B

    gi_kernel<<<B_ * (S_ / 64), 384, 0, stream>>>(inputs, emb, Wih_f, bih_f, bhh_f,
                                                  Wih_b, bih_b, bhh_b, gi);
    encoder_kernel<<<256, 192, 0, stream>>>(gi, Whh_f, bhh_f, Whh_b, bhh_b, outputs, sn);
    t2_kernel<<<128, 128, 0, stream>>>(sn, W2, b2, t2);
    cvt_bf16_kernel<<<H_ * H_ / 1024, 256, 0, stream>>>(W1, W1b);
    cvt_bf16_kernel<<<V_ * H_ / 1024, 256, 0, stream>>>(Wout, Woutb);
    gate_mfma_kernel<<<B_ * S_ / 64, 256, 0, stream>>>(outputs, W1b, b1, t2, enc);
    decoder_kernel<<<128, 512, 0, stream>>>(targets, emb, Wihd, Whhd, bihd, bhhd,
                                            enc, sn, h_all);
    logits_kernel<<<dim3(500, 30), 256, 0, stream>>>(h_all, Woutb, bout, out);
}